// Round 6
// baseline (611.548 us; speedup 1.0000x reference)
//
#include <hip/hip_runtime.h>
#include <stdint.h>

#define Bb 8
#define Nn 256
#define Hh 768
#define Pp 128
#define HEADS 12
#define Dd 64
#define EPSf 1e-5f

typedef __attribute__((ext_vector_type(8))) short bhalf8;   // 8 bf16 (4 VGPRs)
typedef __attribute__((ext_vector_type(4))) float f32x4;

__device__ __forceinline__ unsigned short f2bf(float f) {
    union { float f; unsigned u; } v; v.f = f;
    unsigned r = v.u + 0x7FFFu + ((v.u >> 16) & 1u);
    return (unsigned short)(r >> 16);
}

// ---------------- K0a: 4x transpose fp32 [768][768] -> bf16 n-major ----------------
__global__ __launch_bounds__(256) void k_transpose4(const float* __restrict__ a0, const float* __restrict__ a1,
                                                    const float* __restrict__ a2, const float* __restrict__ a3,
                                                    unsigned short* __restrict__ o0, unsigned short* __restrict__ o1,
                                                    unsigned short* __restrict__ o2, unsigned short* __restrict__ o3) {
    __shared__ float tile[32][33];
    int z = blockIdx.z;
    const float* in = (z == 0) ? a0 : (z == 1) ? a1 : (z == 2) ? a2 : a3;
    unsigned short* out = (z == 0) ? o0 : (z == 1) ? o1 : (z == 2) ? o2 : o3;
    const int R = 768, C = 768;
    int c0 = blockIdx.x * 32, r0 = blockIdx.y * 32;
    int tx = threadIdx.x & 31, ty = threadIdx.x >> 5;
    for (int i = ty; i < 32; i += 8)
        tile[i][tx] = in[(size_t)(r0 + i) * C + c0 + tx];
    __syncthreads();
    for (int i = ty; i < 32; i += 8)
        out[(size_t)(c0 + i) * R + r0 + tx] = f2bf(tile[tx][i]);
}

// ---------------- K0b: 2x transpose fp32 [128][64] -> bf16 [64][128], folding g_path ----------------
__global__ __launch_bounds__(256) void k_transpose_small(const float* __restrict__ a0, const float* __restrict__ a1,
                                                         const float* __restrict__ gp,
                                                         unsigned short* __restrict__ o0, unsigned short* __restrict__ o1) {
    __shared__ float tile[32][33];
    int z = blockIdx.z;
    const float* in = (z == 0) ? a0 : a1;
    unsigned short* out = (z == 0) ? o0 : o1;
    const int R = 128, C = 64;
    int c0 = blockIdx.x * 32, r0 = blockIdx.y * 32;
    int tx = threadIdx.x & 31, ty = threadIdx.x >> 5;
    for (int i = ty; i < 32; i += 8)
        tile[i][tx] = in[(size_t)(r0 + i) * C + c0 + tx];
    __syncthreads();
    float g = gp[r0 + tx];   // input row index (p) = r0+tx after transpose read
    for (int i = ty; i < 32; i += 8)
        out[(size_t)(c0 + i) * R + r0 + tx] = f2bf(tile[tx][i] * g);
}

// ---------------- K0c: bskv2[d] = b_path @ W + bias (struct bias folding) ----------------
__global__ __launch_bounds__(128) void k_prep_bias(const float* __restrict__ Wsk, const float* __restrict__ Wsv,
                                                   const float* __restrict__ bp,
                                                   const float* __restrict__ bsk, const float* __restrict__ bsv,
                                                   float* __restrict__ bskv2) {
    int d = threadIdx.x;          // 0..127
    const float* W = (d < 64) ? Wsk : Wsv;
    int dd = d & 63;
    float s = (d < 64) ? bsk[dd] : bsv[dd];
    for (int p2 = 0; p2 < 128; p2++) s += bp[p2] * W[p2 * 64 + dd];
    bskv2[d] = s;
}

// ---------------- K1: QKV projection, MFMA bf16. V written bf16 transposed vt[b,h,d,k] ----------------
__global__ __launch_bounds__(256) void k_qkv(const float* __restrict__ nodes,
                                             const unsigned short* __restrict__ Wt, // [2304][768] n-major
                                             const float* __restrict__ bq, const float* __restrict__ bk,
                                             const float* __restrict__ bv,
                                             float* __restrict__ qs, float* __restrict__ kk,
                                             unsigned short* __restrict__ vt) {
    __shared__ __align__(16) unsigned short Alds[64 * 72];
    __shared__ __align__(16) unsigned short Blds[128 * 72];
    int tid = threadIdx.x;
    int m0 = blockIdx.y * 64;
    int n0 = blockIdx.x * 128;
    int w = tid >> 6, lane = tid & 63;
    int wm = w >> 1, wn = w & 1;
    int lm = lane & 15, lq = lane >> 4;
    f32x4 acc[2][4];
#pragma unroll
    for (int i = 0; i < 2; i++)
#pragma unroll
        for (int j = 0; j < 4; j++) acc[i][j] = (f32x4){0.f, 0.f, 0.f, 0.f};

    for (int kt = 0; kt < 768; kt += 64) {
#pragma unroll
        for (int t = 0; t < 4; t++) {  // A: 64x64 fp32 -> bf16
            int c = t * 256 + tid;
            int row = c >> 4, cc = c & 15;
            float4 v = *(const float4*)(nodes + (size_t)(m0 + row) * 768 + kt + cc * 4);
            uint2 uu;
            uu.x = (unsigned)f2bf(v.x) | ((unsigned)f2bf(v.y) << 16);
            uu.y = (unsigned)f2bf(v.z) | ((unsigned)f2bf(v.w) << 16);
            *(uint2*)(Alds + row * 72 + cc * 4) = uu;
        }
#pragma unroll
        for (int t = 0; t < 4; t++) {  // B: 128x64 bf16
            int c = t * 256 + tid;
            int n = c >> 3, kc = c & 7;
            uint4 v = *(const uint4*)(Wt + (size_t)(n0 + n) * 768 + kt + kc * 8);
            *(uint4*)(Blds + n * 72 + kc * 8) = v;
        }
        __syncthreads();
#pragma unroll
        for (int ks = 0; ks < 2; ks++) {
            bhalf8 af[2];
#pragma unroll
            for (int mi = 0; mi < 2; mi++)
                af[mi] = *(const bhalf8*)(Alds + (wm * 32 + mi * 16 + lm) * 72 + ks * 32 + lq * 8);
#pragma unroll
            for (int nt = 0; nt < 4; nt++) {
                bhalf8 bf = *(const bhalf8*)(Blds + (wn * 64 + nt * 16 + lm) * 72 + ks * 32 + lq * 8);
#pragma unroll
                for (int mi = 0; mi < 2; mi++)
                    acc[mi][nt] = __builtin_amdgcn_mfma_f32_16x16x32_bf16(af[mi], bf, acc[mi][nt], 0, 0, 0);
            }
        }
        __syncthreads();
    }
    int wsel = n0 / 768;
    int nb = n0 % 768;
    if (wsel == 2) {
        // V: bf16, transposed layout vt[((b*12+h)*64+d)*256 + q]
#pragma unroll
        for (int mi = 0; mi < 2; mi++)
#pragma unroll
            for (int nt = 0; nt < 4; nt++)
#pragma unroll
                for (int r = 0; r < 4; r++) {
                    int row = m0 + wm * 32 + mi * 16 + lq * 4 + r;
                    int col = nb + wn * 64 + nt * 16 + lm;
                    int hh = col >> 6, d = col & 63;
                    int b = row >> 8, qn = row & 255;
                    float val = acc[mi][nt][r] + bv[col];
                    vt[(((size_t)b * HEADS + hh) * Dd + d) * Nn + qn] = f2bf(val);
                }
    } else {
        const float* bias = (wsel == 0) ? bq : bk;
        float* dst = (wsel == 0) ? qs : kk;
        float scale = (wsel == 0) ? 0.125f : 1.0f;
#pragma unroll
        for (int mi = 0; mi < 2; mi++)
#pragma unroll
            for (int nt = 0; nt < 4; nt++)
#pragma unroll
                for (int r = 0; r < 4; r++) {
                    int row = m0 + wm * 32 + mi * 16 + lq * 4 + r;
                    int col = nb + wn * 64 + nt * 16 + lm;
                    int hh = col >> 6, d = col & 63;
                    int b = row >> 8, qn = row & 255;
                    float val = (acc[mi][nt][r] + bias[col]) * scale;
                    dst[(((size_t)b * HEADS + hh) * Nn + qn) * Dd + d] = val;
                }
    }
}

// ---------------- K2: content scores + bias, MFMA ----------------
__global__ __launch_bounds__(256) void k_scores(const float* __restrict__ qs,
                                                const float* __restrict__ kk,
                                                const float* __restrict__ bias,
                                                float* __restrict__ wg) {
    __shared__ __align__(16) unsigned short Alds[64 * 72];
    __shared__ __align__(16) unsigned short Blds[64 * 72];
    int tid = threadIdx.x;
    int bh = blockIdx.z;
    int m0 = blockIdx.y * 64;
    int n0 = blockIdx.x * 64;
    int w = tid >> 6, lane = tid & 63, lm = lane & 15, lq = lane >> 4;
    const float* Abase = qs + ((size_t)bh * Nn + m0) * Dd;
    const float* Bbase = kk + ((size_t)bh * Nn + n0) * Dd;
#pragma unroll
    for (int t = 0; t < 4; t++) {
        int c = t * 256 + tid;
        int row = c >> 4, cc = c & 15;
        float4 va = *(const float4*)(Abase + (size_t)row * 64 + cc * 4);
        uint2 ua;
        ua.x = (unsigned)f2bf(va.x) | ((unsigned)f2bf(va.y) << 16);
        ua.y = (unsigned)f2bf(va.z) | ((unsigned)f2bf(va.w) << 16);
        *(uint2*)(Alds + row * 72 + cc * 4) = ua;
        float4 vb = *(const float4*)(Bbase + (size_t)row * 64 + cc * 4);
        uint2 ub;
        ub.x = (unsigned)f2bf(vb.x) | ((unsigned)f2bf(vb.y) << 16);
        ub.y = (unsigned)f2bf(vb.z) | ((unsigned)f2bf(vb.w) << 16);
        *(uint2*)(Blds + row * 72 + cc * 4) = ub;
    }
    __syncthreads();
    f32x4 acc[4];
#pragma unroll
    for (int i = 0; i < 4; i++) acc[i] = (f32x4){0.f, 0.f, 0.f, 0.f};
#pragma unroll
    for (int ks = 0; ks < 2; ks++) {
        bhalf8 af = *(const bhalf8*)(Alds + (w * 16 + lm) * 72 + ks * 32 + lq * 8);
#pragma unroll
        for (int nt = 0; nt < 4; nt++) {
            bhalf8 bf = *(const bhalf8*)(Blds + (nt * 16 + lm) * 72 + ks * 32 + lq * 8);
            acc[nt] = __builtin_amdgcn_mfma_f32_16x16x32_bf16(af, bf, acc[nt], 0, 0, 0);
        }
    }
#pragma unroll
    for (int nt = 0; nt < 4; nt++)
#pragma unroll
        for (int r = 0; r < 4; r++) {
            int row = m0 + w * 16 + lq * 4 + r;
            int col = n0 + nt * 16 + lm;
            size_t idx = ((size_t)bh * Nn + row) * Nn + col;
            wg[idx] = acc[nt][r] + bias[idx];
        }
}

// ---------------- K4 (fused, 512 threads / 8 waves): path LN + struct proj + scores + softmax + struct out ----
// One block per (b,q). Wave w owns path/k rows [32w, 32w+32).
// Latency discipline (R4 post-mortem): two-pass LN (pass1 = stats with rolling window so the 16
// HBM loads pipeline deep; pass2 = L2-hit reload -> bf16 frags). wg content scores issued at
// kernel top so their HBM latency hides under the projection. Barrier between proj and MFMA1
// removed: each wave reads only the SK rows it wrote itself (same-wave LDS ops are in-order).
__global__ __launch_bounds__(512, 2) void k_attn(const float* __restrict__ qs,
                                                 const float* __restrict__ paths,
                                                 const unsigned short* __restrict__ Wskvt, // [128 n][128 k] n-major, g-folded
                                                 const float* __restrict__ bskv2,          // [128] folded bias
                                                 const float* __restrict__ wg,             // fp32 content scores (in)
                                                 unsigned short* __restrict__ wgbf,        // bf16 probs (out)
                                                 float* __restrict__ attn) {
    __shared__ __align__(16) unsigned short SKbuf[256 * 72];   // SK [256][72]; later aliased as SVT [64][264]
    __shared__ __align__(16) unsigned short A2[16 * 264];
    __shared__ float redm[16 * 8];   // [16 rows][8 w]
    __shared__ float reds[16 * 8];
    unsigned short* SVT = SKbuf;

    int tid = threadIdx.x;
    int bq = blockIdx.x;
    int b = bq >> 8, q = bq & 255;
    int w = tid >> 6, lane = tid & 63, lm = lane & 15, lq = lane >> 4;

    const float* ppath = paths + (size_t)bq * (256 * 128);

    // ---- early-issue content scores (cold HBM, scattered) so latency hides under proj ----
    size_t wbase = ((size_t)b * HEADS) * (Nn * Nn) + (size_t)q * Nn;
    float wgv[2][4];
#pragma unroll
    for (int nt = 0; nt < 2; nt++) {
        int col = w * 32 + nt * 16 + lm;
#pragma unroll
        for (int r = 0; r < 4; r++) {
            int row = lq * 4 + r;
            wgv[nt][r] = (row < 12) ? wg[wbase + (size_t)row * (Nn * Nn) + col] : 0.f;
        }
    }

    // ---- Phase A pass 1: LN stats with rolling window (no x[32] -> loads pipeline deep) ----
    float mu_[2], rs_[2];
    {
        const float* pr0 = ppath + (size_t)(w * 32 + lm) * 128;
        const float* pr1 = ppath + (size_t)(w * 32 + 16 + lm) * 128;
        float s0 = 0.f, q0 = 0.f, s1 = 0.f, q1 = 0.f;
#pragma unroll
        for (int ks = 0; ks < 4; ks++) {
            float4 a0 = *(const float4*)(pr0 + ks * 32 + lq * 8);
            float4 c0 = *(const float4*)(pr0 + ks * 32 + lq * 8 + 4);
            float4 a1 = *(const float4*)(pr1 + ks * 32 + lq * 8);
            float4 c1 = *(const float4*)(pr1 + ks * 32 + lq * 8 + 4);
            s0 += (a0.x + a0.y) + (a0.z + a0.w) + (c0.x + c0.y) + (c0.z + c0.w);
            q0 += a0.x * a0.x + a0.y * a0.y + a0.z * a0.z + a0.w * a0.w
                + c0.x * c0.x + c0.y * c0.y + c0.z * c0.z + c0.w * c0.w;
            s1 += (a1.x + a1.y) + (a1.z + a1.w) + (c1.x + c1.y) + (c1.z + c1.w);
            q1 += a1.x * a1.x + a1.y * a1.y + a1.z * a1.z + a1.w * a1.w
                + c1.x * c1.x + c1.y * c1.y + c1.z * c1.z + c1.w * c1.w;
        }
        s0 += __shfl_xor(s0, 16); q0 += __shfl_xor(q0, 16);
        s0 += __shfl_xor(s0, 32); q0 += __shfl_xor(q0, 32);
        s1 += __shfl_xor(s1, 16); q1 += __shfl_xor(q1, 16);
        s1 += __shfl_xor(s1, 32); q1 += __shfl_xor(q1, 32);
        mu_[0] = s0 * (1.f / 128.f);
        rs_[0] = rsqrtf(q0 * (1.f / 128.f) - mu_[0] * mu_[0] + EPSf);
        mu_[1] = s1 * (1.f / 128.f);
        rs_[1] = rsqrtf(q1 * (1.f / 128.f) - mu_[1] * mu_[1] + EPSf);
    }
    // ---- Phase A pass 2: reload (L2-hit) and build bf16 A-fragments ----
    bhalf8 afr[2][4];
#pragma unroll
    for (int mi = 0; mi < 2; mi++) {
        const float* pr = ppath + (size_t)(w * 32 + mi * 16 + lm) * 128;
        float mu = mu_[mi], rs = rs_[mi];
#pragma unroll
        for (int ks = 0; ks < 4; ks++) {
            float4 a = *(const float4*)(pr + ks * 32 + lq * 8);
            float4 c = *(const float4*)(pr + ks * 32 + lq * 8 + 4);
            bhalf8 t;
            t[0] = (short)f2bf((a.x - mu) * rs); t[1] = (short)f2bf((a.y - mu) * rs);
            t[2] = (short)f2bf((a.z - mu) * rs); t[3] = (short)f2bf((a.w - mu) * rs);
            t[4] = (short)f2bf((c.x - mu) * rs); t[5] = (short)f2bf((c.y - mu) * rs);
            t[6] = (short)f2bf((c.z - mu) * rs); t[7] = (short)f2bf((c.w - mu) * rs);
            afr[mi][ks] = t;
        }
    }

    // ---- Phase B1: SK pass (Wskvt rows 0..63), write straight to LDS ----
    {
        f32x4 acc[2][4];
#pragma unroll
        for (int i = 0; i < 2; i++)
#pragma unroll
            for (int j = 0; j < 4; j++) acc[i][j] = (f32x4){0.f, 0.f, 0.f, 0.f};
#pragma unroll
        for (int ks = 0; ks < 4; ks++) {
#pragma unroll
            for (int nt = 0; nt < 4; nt++) {
                bhalf8 bf = *(const bhalf8*)(Wskvt + (size_t)(nt * 16 + lm) * 128 + ks * 32 + lq * 8);
#pragma unroll
                for (int mi = 0; mi < 2; mi++)
                    acc[mi][nt] = __builtin_amdgcn_mfma_f32_16x16x32_bf16(afr[mi][ks], bf, acc[mi][nt], 0, 0, 0);
            }
        }
#pragma unroll
        for (int mi = 0; mi < 2; mi++)
#pragma unroll
            for (int nt = 0; nt < 4; nt++) {
                int col = nt * 16 + lm;
                float bb = bskv2[col];
#pragma unroll
                for (int rr = 0; rr < 4; rr++) {
                    int R2 = w * 32 + mi * 16 + lq * 4 + rr;
                    SKbuf[R2 * 72 + col] = f2bf(acc[mi][nt][rr] + bb);
                }
            }
    }

    // ---- Phase B2: SV pass (Wskvt rows 64..127), keep in registers ----
    f32x4 accSV[2][4];
#pragma unroll
    for (int i = 0; i < 2; i++)
#pragma unroll
        for (int j = 0; j < 4; j++) accSV[i][j] = (f32x4){0.f, 0.f, 0.f, 0.f};
#pragma unroll
    for (int ks = 0; ks < 4; ks++) {
#pragma unroll
        for (int nt = 0; nt < 4; nt++) {
            bhalf8 bf = *(const bhalf8*)(Wskvt + (size_t)(64 + nt * 16 + lm) * 128 + ks * 32 + lq * 8);
#pragma unroll
            for (int mi = 0; mi < 2; mi++)
                accSV[mi][nt] = __builtin_amdgcn_mfma_f32_16x16x32_bf16(afr[mi][ks], bf, accSV[mi][nt], 0, 0, 0);
        }
    }

    // NOTE: no barrier here. MFMA1 wave w reads only SK rows [32w,32w+32) which wave w itself
    // wrote in B1; same-wave LDS ops execute in order. Cross-wave hazards start at the SVT
    // overwrite, which is guarded by the barrier below.

    // ---- Q fragments for MFMA1 (loaded late to keep them out of the proj live range) ----
    bhalf8 af1[2];
    {
        bhalf8 z = (bhalf8){0, 0, 0, 0, 0, 0, 0, 0};
        af1[0] = z; af1[1] = z;
        if (lm < 12) {
            const float* qp = qs + (((size_t)b * HEADS + lm) * Nn + q) * Dd;
#pragma unroll
            for (int ks = 0; ks < 2; ks++) {
                float4 v0 = *(const float4*)(qp + ks * 32 + lq * 8);
                float4 v1 = *(const float4*)(qp + ks * 32 + lq * 8 + 4);
                bhalf8 t;
                t[0] = (short)f2bf(v0.x); t[1] = (short)f2bf(v0.y);
                t[2] = (short)f2bf(v0.z); t[3] = (short)f2bf(v0.w);
                t[4] = (short)f2bf(v1.x); t[5] = (short)f2bf(v1.y);
                t[6] = (short)f2bf(v1.z); t[7] = (short)f2bf(v1.w);
                af1[ks] = t;
            }
        }
    }

    // ---- MFMA1: struct scores S[16 h][256 k] (wave w covers k in [32w, 32w+32)) + content scores ----
    f32x4 acc1[2];
#pragma unroll
    for (int i = 0; i < 2; i++) acc1[i] = (f32x4){0.f, 0.f, 0.f, 0.f};
#pragma unroll
    for (int ks = 0; ks < 2; ks++) {
#pragma unroll
        for (int nt = 0; nt < 2; nt++) {
            int n0 = w * 32 + nt * 16;
            bhalf8 bf = *(const bhalf8*)(SKbuf + (n0 + lm) * 72 + ks * 32 + lq * 8);
            acc1[nt] = __builtin_amdgcn_mfma_f32_16x16x32_bf16(af1[ks], bf, acc1[nt], 0, 0, 0);
        }
    }
    float S[2][4];
#pragma unroll
    for (int nt = 0; nt < 2; nt++)
#pragma unroll
        for (int r = 0; r < 4; r++) S[nt][r] = acc1[nt][r] + wgv[nt][r];

    // ---- SK region free after this barrier: write SV transposed SVT[64 d][264 k] ----
    __syncthreads();
#pragma unroll
    for (int mi = 0; mi < 2; mi++)
#pragma unroll
        for (int nt = 0; nt < 4; nt++) {
            int d = nt * 16 + lm;
            float bb = bskv2[64 + d];
#pragma unroll
            for (int rr = 0; rr < 4; rr++) {
                int R2 = w * 32 + mi * 16 + lq * 4 + rr;
                SVT[d * 264 + R2] = f2bf(accSV[mi][nt][rr] + bb);
            }
        }

    // ---- softmax over 256 cols per row (8 waves x 32 cols) ----
    float m4[4];
#pragma unroll
    for (int r = 0; r < 4; r++)
        m4[r] = fmaxf(S[0][r], S[1][r]);
#pragma unroll
    for (int mk = 1; mk < 16; mk <<= 1)
#pragma unroll
        for (int r = 0; r < 4; r++) m4[r] = fmaxf(m4[r], __shfl_xor(m4[r], mk));
    if (lm == 0) {
#pragma unroll
        for (int r = 0; r < 4; r++) redm[(lq * 4 + r) * 8 + w] = m4[r];
    }
    __syncthreads();
    float rowmax[4];
#pragma unroll
    for (int r = 0; r < 4; r++) {
        int row = lq * 4 + r;
        float a = fmaxf(fmaxf(redm[row * 8 + 0], redm[row * 8 + 1]), fmaxf(redm[row * 8 + 2], redm[row * 8 + 3]));
        float c = fmaxf(fmaxf(redm[row * 8 + 4], redm[row * 8 + 5]), fmaxf(redm[row * 8 + 6], redm[row * 8 + 7]));
        rowmax[r] = fmaxf(a, c);
    }
    float P[2][4], psum[4];
#pragma unroll
    for (int r = 0; r < 4; r++) {
#pragma unroll
        for (int nt = 0; nt < 2; nt++) P[nt][r] = __expf(S[nt][r] - rowmax[r]);
        psum[r] = P[0][r] + P[1][r];
    }
#pragma unroll
    for (int mk = 1; mk < 16; mk <<= 1)
#pragma unroll
        for (int r = 0; r < 4; r++) psum[r] += __shfl_xor(psum[r], mk);
    if (lm == 0) {
#pragma unroll
        for (int r = 0; r < 4; r++) reds[(lq * 4 + r) * 8 + w] = psum[r];
    }
    __syncthreads();
    float inv[4];
#pragma unroll
    for (int r = 0; r < 4; r++) {
        int row = lq * 4 + r;
        float a = (reds[row * 8 + 0] + reds[row * 8 + 1]) + (reds[row * 8 + 2] + reds[row * 8 + 3]);
        float c = (reds[row * 8 + 4] + reds[row * 8 + 5]) + (reds[row * 8 + 6] + reds[row * 8 + 7]);
        inv[r] = 1.f / (a + c);
    }
    // probs: bf16 into A2 (MFMA2 A-operand) and into wgbf for K5
#pragma unroll
    for (int nt = 0; nt < 2; nt++)
#pragma unroll
        for (int r = 0; r < 4; r++) {
            int row = lq * 4 + r;
            int col = w * 32 + nt * 16 + lm;
            float pv = P[nt][r] * inv[r];
            unsigned short pb = f2bf(pv);
            A2[row * 264 + col] = pb;
            if (row < 12) wgbf[wbase + (size_t)row * (Nn * Nn) + col] = pb;
        }
    __syncthreads();

    // ---- MFMA2 (waves 0..3): O[16 h][64 d] = P[16,256] @ SV[256,64]; wave w -> d-tile w*16 ----
    if (w < 4) {
        f32x4 acc2 = (f32x4){0.f, 0.f, 0.f, 0.f};
#pragma unroll
        for (int ks = 0; ks < 8; ks++) {
            bhalf8 af = *(const bhalf8*)(A2 + lm * 264 + ks * 32 + lq * 8);
            bhalf8 bf = *(const bhalf8*)(SVT + (w * 16 + lm) * 264 + ks * 32 + lq * 8);
            acc2 = __builtin_amdgcn_mfma_f32_16x16x32_bf16(af, bf, acc2, 0, 0, 0);
        }
#pragma unroll
        for (int r = 0; r < 4; r++) {
            int row = lq * 4 + r;
            if (row < 12) attn[(size_t)bq * Hh + row * 64 + w * 16 + lm] = acc2[r];
        }
    }
}

// ---------------- K5: content out = P(bf16) @ V(bf16), MFMA, accumulate into attn ----------------
__global__ __launch_bounds__(256) void k_ctxout(const unsigned short* __restrict__ wgbf, // [b,h,q,k] bf16
                                                const unsigned short* __restrict__ vt,   // [b,h,d,k] bf16
                                                float* __restrict__ attn) {
    __shared__ __align__(16) unsigned short Alds[64 * 72];
    __shared__ __align__(16) unsigned short Blds[64 * 72];
    int tid = threadIdx.x;
    int bh = blockIdx.y;
    int m0 = blockIdx.x * 64;
    int b = bh / 12, h = bh % 12;
    int w = tid >> 6, lane = tid & 63, lm = lane & 15, lq = lane >> 4;
    f32x4 acc[4];
#pragma unroll
    for (int i = 0; i < 4; i++) acc[i] = (f32x4){0.f, 0.f, 0.f, 0.f};
    const unsigned short* Abase = wgbf + ((size_t)bh * Nn + m0) * Nn;
    const unsigned short* Bbase = vt + (size_t)bh * Dd * Nn;
    for (int kt = 0; kt < 256; kt += 64) {
#pragma unroll
        for (int t = 0; t < 2; t++) {
            int c = t * 256 + tid;
            int row = c >> 3, kc = c & 7;
            *(uint4*)(Alds + row * 72 + kc * 8) = *(const uint4*)(Abase + (size_t)row * Nn + kt + kc * 8);
            *(uint4*)(Blds + row * 72 + kc * 8) = *(const uint4*)(Bbase + (size_t)row * Nn + kt + kc * 8);
        }
        __syncthreads();
#pragma unroll
        for (int ks = 0; ks < 2; ks++) {
            bhalf8 af = *(const bhalf8*)(Alds + (w * 16 + lm) * 72 + ks * 32 + lq * 8);
#pragma unroll
            for (int nt = 0; nt < 4; nt++) {
                bhalf8 bf = *(const bhalf8*)(Blds + (nt * 16 + lm) * 72 + ks * 32 + lq * 8);
                acc[nt] = __builtin_amdgcn_mfma_f32_16x16x32_bf16(af, bf, acc[nt], 0, 0, 0);
            }
        }
        __syncthreads();
    }
#pragma unroll
    for (int nt = 0; nt < 4; nt++)
#pragma unroll
        for (int r = 0; r < 4; r++) {
            int row = m0 + w * 16 + lq * 4 + r;
            int col = nt * 16 + lm;
            size_t o = ((size_t)b * Nn + row) * Hh + h * 64 + col;
            attn[o] += acc[nt][r];
        }
}

// ---------------- K6: out projection + bias + relu + residual, MFMA ----------------
__global__ __launch_bounds__(256) void k_outproj(const float* __restrict__ attn,
                                                 const unsigned short* __restrict__ Wot, // [768][768] n-major
                                                 const float* __restrict__ bo,
                                                 const float* __restrict__ nodes,
                                                 float* __restrict__ tmp) {
    __shared__ __align__(16) unsigned short Alds[64 * 72];
    __shared__ __align__(16) unsigned short Blds[128 * 72];
    int tid = threadIdx.x;
    int m0 = blockIdx.y * 64;
    int n0 = blockIdx.x * 128;
    int w = tid >> 6, lane = tid & 63;
    int wm = w >> 1, wn = w & 1;
    int lm = lane & 15, lq = lane >> 4;
    f32x4 acc[2][4];
#pragma unroll
    for (int i = 0; i < 2; i++)
#pragma unroll
        for (int j = 0; j < 4; j++) acc[i][j] = (f32x4){0.f, 0.f, 0.f, 0.f};
    for (int kt = 0; kt < 768; kt += 64) {
#pragma unroll
        for (int t = 0; t < 4; t++) {
            int c = t * 256 + tid;
            int row = c >> 4, cc = c & 15;
            float4 v = *(const float4*)(attn + (size_t)(m0 + row) * 768 + kt + cc * 4);
            uint2 uu;
            uu.x = (unsigned)f2bf(v.x) | ((unsigned)f2bf(v.y) << 16);
            uu.y = (unsigned)f2bf(v.z) | ((unsigned)f2bf(v.w) << 16);
            *(uint2*)(Alds + row * 72 + cc * 4) = uu;
        }
#pragma unroll
        for (int t = 0; t < 4; t++) {
            int c = t * 256 + tid;
            int n = c >> 3, kc = c & 7;
            uint4 v = *(const uint4*)(Wot + (size_t)(n0 + n) * 768 + kt + kc * 8);
            *(uint4*)(Blds + n * 72 + kc * 8) = v;
        }
        __syncthreads();
#pragma unroll
        for (int ks = 0; ks < 2; ks++) {
            bhalf8 af[2];
#pragma unroll
            for (int mi = 0; mi < 2; mi++)
                af[mi] = *(const bhalf8*)(Alds + (wm * 32 + mi * 16 + lm) * 72 + ks * 32 + lq * 8);
#pragma unroll
            for (int nt = 0; nt < 4; nt++) {
                bhalf8 bf = *(const bhalf8*)(Blds + (wn * 64 + nt * 16 + lm) * 72 + ks * 32 + lq * 8);
#pragma unroll
                for (int mi = 0; mi < 2; mi++)
                    acc[mi][nt] = __builtin_amdgcn_mfma_f32_16x16x32_bf16(af[mi], bf, acc[mi][nt], 0, 0, 0);
            }
        }
        __syncthreads();
    }
#pragma unroll
    for (int mi = 0; mi < 2; mi++)
#pragma unroll
        for (int nt = 0; nt < 4; nt++)
#pragma unroll
            for (int r = 0; r < 4; r++) {
                int row = m0 + wm * 32 + mi * 16 + lq * 4 + r;
                int col = n0 + wn * 64 + nt * 16 + lm;
                float val = acc[mi][nt][r] + bo[col];
                val = fmaxf(val, 0.f) + nodes[(size_t)row * 768 + col];
                tmp[(size_t)row * 768 + col] = val;
            }
}

// ---------------- K7: final row LayerNorm ----------------
__global__ __launch_bounds__(256) void k_finalln(const float* __restrict__ tmp,
                                                 const float* __restrict__ go,
                                                 const float* __restrict__ bout,
                                                 float* __restrict__ out) {
    __shared__ float rs1[4], rs2[4];
    int m = blockIdx.x, tid = threadIdx.x;
    int lane = tid & 63, wid = tid >> 6;
    const float* row = tmp + (size_t)m * 768;
    float x0 = row[tid], x1 = row[tid + 256], x2 = row[tid + 512];
    float s = x0 + x1 + x2;
    float s2 = x0 * x0 + x1 * x1 + x2 * x2;
#pragma unroll
    for (int mk = 32; mk; mk >>= 1) {
        s += __shfl_xor(s, mk);
        s2 += __shfl_xor(s2, mk);
    }
    if (lane == 0) { rs1[wid] = s; rs2[wid] = s2; }
    __syncthreads();
    s = rs1[0] + rs1[1] + rs1[2] + rs1[3];
    s2 = rs2[0] + rs2[1] + rs2[2] + rs2[3];
    float mu = s * (1.f / 768.f);
    float var = s2 * (1.f / 768.f) - mu * mu;
    float rstd = rsqrtf(var + EPSf);
    float* orow = out + (size_t)m * 768;
    orow[tid] = (x0 - mu) * rstd * go[tid] + bout[tid];
    orow[tid + 256] = (x1 - mu) * rstd * go[tid + 256] + bout[tid + 256];
    orow[tid + 512] = (x2 - mu) * rstd * go[tid + 512] + bout[tid + 512];
}

extern "C" void kernel_launch(void* const* d_in, const int* in_sizes, int n_in,
                              void* d_out, int out_size, void* d_ws, size_t ws_size,
                              hipStream_t stream) {
    const float* nodes = (const float*)d_in[0];
    const float* bias  = (const float*)d_in[1];
    const float* paths = (const float*)d_in[2];
    const float* Wq = (const float*)d_in[3];  const float* bq  = (const float*)d_in[4];
    const float* Wk = (const float*)d_in[5];  const float* bk  = (const float*)d_in[6];
    const float* Wv = (const float*)d_in[7];  const float* bv  = (const float*)d_in[8];
    const float* Wsk = (const float*)d_in[9]; const float* bsk = (const float*)d_in[10];
    const float* Wsv = (const float*)d_in[11];const float* bsv = (const float*)d_in[12];
    const float* Wo = (const float*)d_in[13]; const float* bo  = (const float*)d_in[14];
    const float* gp = (const float*)d_in[15]; const float* bp  = (const float*)d_in[16];
    const float* go = (const float*)d_in[17]; const float* bout= (const float*)d_in[18];
    float* out = (float*)d_out;

    char* ws = (char*)d_ws;
    size_t off = 0;
    auto carve = [&](size_t bytes) -> char* {
        char* p = ws + off;
        off += (bytes + 255) & ~(size_t)255;
        return p;
    };
    float* qs   = (float*)carve((size_t)Bb * HEADS * Nn * Dd * 4);
    float* kk   = (float*)carve((size_t)Bb * HEADS * Nn * Dd * 4);
    unsigned short* vt = (unsigned short*)carve((size_t)Bb * HEADS * Dd * Nn * 2);
    float* wg   = (float*)carve((size_t)Bb * HEADS * Nn * Nn * 4);
    unsigned short* wgbf = (unsigned short*)carve((size_t)Bb * HEADS * Nn * Nn * 2);
    float* attn = (float*)carve((size_t)Bb * Nn * Hh * 4);
    float* tmp  = (float*)carve((size_t)Bb * Nn * Hh * 4);
    unsigned short* Wqkvt = (unsigned short*)carve((size_t)3 * 768 * 768 * 2);
    unsigned short* Wot   = (unsigned short*)carve((size_t)768 * 768 * 2);
    unsigned short* Wskvt = (unsigned short*)carve((size_t)128 * 128 * 2);
    float* bskv2 = (float*)carve(128 * 4);
    (void)ws_size; (void)in_sizes; (void)n_in; (void)out_size;

    // K0: weight transposes (fp32 -> bf16, n-major); g_path folded into Wskvt; bias' = bp@W + bskv
    hipLaunchKernelGGL(k_transpose4, dim3(24, 24, 4), dim3(256), 0, stream,
                       Wq, Wk, Wv, Wo,
                       Wqkvt, Wqkvt + (size_t)768 * 768, Wqkvt + (size_t)2 * 768 * 768, Wot);
    hipLaunchKernelGGL(k_transpose_small, dim3(2, 4, 2), dim3(256), 0, stream,
                       Wsk, Wsv, gp, Wskvt, Wskvt + (size_t)64 * 128);
    hipLaunchKernelGGL(k_prep_bias, dim3(1), dim3(128), 0, stream,
                       Wsk, Wsv, bp, bsk, bsv, bskv2);

    // K1: QKV (V -> bf16 transposed vt)
    hipLaunchKernelGGL(k_qkv, dim3(18, 32), dim3(256), 0, stream, nodes, Wqkvt, bq, bk, bv, qs, kk, vt);
    // K2: content scores + bias (fp32)
    hipLaunchKernelGGL(k_scores, dim3(4, 4, 96), dim3(256), 0, stream, qs, kk, bias, wg);
    // K4 (fused, 512 thr): path LN + struct proj + struct scores + softmax + struct out
    hipLaunchKernelGGL(k_attn, dim3(2048), dim3(512), 0, stream, qs, paths, Wskvt, bskv2, wg, wgbf, attn);
    // K5: content out accumulate (MFMA bf16)
    hipLaunchKernelGGL(k_ctxout, dim3(4, 96), dim3(256), 0, stream, wgbf, vt, attn);
    // K6: output projection + relu + residual
    hipLaunchKernelGGL(k_outproj, dim3(6, 32), dim3(256), 0, stream, attn, Wot, bo, nodes, tmp);
    // K7: final layernorm
    hipLaunchKernelGGL(k_finalln, dim3(2048), dim3(256), 0, stream, tmp, go, bout, out);
}

// Round 7
// 558.562 us; speedup vs baseline: 1.0949x; 1.0949x over previous
//
#include <hip/hip_runtime.h>
#include <stdint.h>

#define Bb 8
#define Nn 256
#define Hh 768
#define Pp 128
#define HEADS 12
#define Dd 64
#define EPSf 1e-5f

typedef __attribute__((ext_vector_type(8))) short bhalf8;   // 8 bf16 (4 VGPRs)
typedef __attribute__((ext_vector_type(4))) float f32x4;

__device__ __forceinline__ unsigned short f2bf(float f) {
    union { float f; unsigned u; } v; v.f = f;
    unsigned r = v.u + 0x7FFFu + ((v.u >> 16) & 1u);
    return (unsigned short)(r >> 16);
}

// XOR swizzle on ushort column index: flips byte bits 4..6 with row bits 0..2.
// Applied identically on write and read -> bijective within each 128B-aligned row stripe.
__device__ __forceinline__ int swz(int row, int colUs) {
    return colUs ^ ((row & 7) << 3);
}

// ---------------- K0a: 4x transpose fp32 [768][768] -> bf16 n-major ----------------
__global__ __launch_bounds__(256) void k_transpose4(const float* __restrict__ a0, const float* __restrict__ a1,
                                                    const float* __restrict__ a2, const float* __restrict__ a3,
                                                    unsigned short* __restrict__ o0, unsigned short* __restrict__ o1,
                                                    unsigned short* __restrict__ o2, unsigned short* __restrict__ o3) {
    __shared__ float tile[32][33];
    int z = blockIdx.z;
    const float* in = (z == 0) ? a0 : (z == 1) ? a1 : (z == 2) ? a2 : a3;
    unsigned short* out = (z == 0) ? o0 : (z == 1) ? o1 : (z == 2) ? o2 : o3;
    const int R = 768, C = 768;
    int c0 = blockIdx.x * 32, r0 = blockIdx.y * 32;
    int tx = threadIdx.x & 31, ty = threadIdx.x >> 5;
    for (int i = ty; i < 32; i += 8)
        tile[i][tx] = in[(size_t)(r0 + i) * C + c0 + tx];
    __syncthreads();
    for (int i = ty; i < 32; i += 8)
        out[(size_t)(c0 + i) * R + r0 + tx] = f2bf(tile[tx][i]);
}

// ---------------- K0b: 2x transpose fp32 [128][64] -> bf16 [64][128], folding g_path ----------------
__global__ __launch_bounds__(256) void k_transpose_small(const float* __restrict__ a0, const float* __restrict__ a1,
                                                         const float* __restrict__ gp,
                                                         unsigned short* __restrict__ o0, unsigned short* __restrict__ o1) {
    __shared__ float tile[32][33];
    int z = blockIdx.z;
    const float* in = (z == 0) ? a0 : a1;
    unsigned short* out = (z == 0) ? o0 : o1;
    const int R = 128, C = 64;
    int c0 = blockIdx.x * 32, r0 = blockIdx.y * 32;
    int tx = threadIdx.x & 31, ty = threadIdx.x >> 5;
    for (int i = ty; i < 32; i += 8)
        tile[i][tx] = in[(size_t)(r0 + i) * C + c0 + tx];
    __syncthreads();
    float g = gp[r0 + tx];   // input row index (p) = r0+tx after transpose read
    for (int i = ty; i < 32; i += 8)
        out[(size_t)(c0 + i) * R + r0 + tx] = f2bf(tile[tx][i] * g);
}

// ---------------- K0c: bskv2[d] = b_path @ W + bias (struct bias folding) ----------------
__global__ __launch_bounds__(128) void k_prep_bias(const float* __restrict__ Wsk, const float* __restrict__ Wsv,
                                                   const float* __restrict__ bp,
                                                   const float* __restrict__ bsk, const float* __restrict__ bsv,
                                                   float* __restrict__ bskv2) {
    int d = threadIdx.x;          // 0..127
    const float* W = (d < 64) ? Wsk : Wsv;
    int dd = d & 63;
    float s = (d < 64) ? bsk[dd] : bsv[dd];
    for (int p2 = 0; p2 < 128; p2++) s += bp[p2] * W[p2 * 64 + dd];
    bskv2[d] = s;
}

// ---------------- K1: QKV projection, MFMA bf16. V written bf16 transposed vt[b,h,d,k] ----------------
__global__ __launch_bounds__(256) void k_qkv(const float* __restrict__ nodes,
                                             const unsigned short* __restrict__ Wt, // [2304][768] n-major
                                             const float* __restrict__ bq, const float* __restrict__ bk,
                                             const float* __restrict__ bv,
                                             float* __restrict__ qs, float* __restrict__ kk,
                                             unsigned short* __restrict__ vt) {
    __shared__ __align__(16) unsigned short Alds[64 * 72];
    __shared__ __align__(16) unsigned short Blds[128 * 72];
    int tid = threadIdx.x;
    int m0 = blockIdx.y * 64;
    int n0 = blockIdx.x * 128;
    int w = tid >> 6, lane = tid & 63;
    int wm = w >> 1, wn = w & 1;
    int lm = lane & 15, lq = lane >> 4;
    f32x4 acc[2][4];
#pragma unroll
    for (int i = 0; i < 2; i++)
#pragma unroll
        for (int j = 0; j < 4; j++) acc[i][j] = (f32x4){0.f, 0.f, 0.f, 0.f};

    for (int kt = 0; kt < 768; kt += 64) {
#pragma unroll
        for (int t = 0; t < 4; t++) {  // A: 64x64 fp32 -> bf16
            int c = t * 256 + tid;
            int row = c >> 4, cc = c & 15;
            float4 v = *(const float4*)(nodes + (size_t)(m0 + row) * 768 + kt + cc * 4);
            uint2 uu;
            uu.x = (unsigned)f2bf(v.x) | ((unsigned)f2bf(v.y) << 16);
            uu.y = (unsigned)f2bf(v.z) | ((unsigned)f2bf(v.w) << 16);
            *(uint2*)(Alds + row * 72 + cc * 4) = uu;
        }
#pragma unroll
        for (int t = 0; t < 4; t++) {  // B: 128x64 bf16
            int c = t * 256 + tid;
            int n = c >> 3, kc = c & 7;
            uint4 v = *(const uint4*)(Wt + (size_t)(n0 + n) * 768 + kt + kc * 8);
            *(uint4*)(Blds + n * 72 + kc * 8) = v;
        }
        __syncthreads();
#pragma unroll
        for (int ks = 0; ks < 2; ks++) {
            bhalf8 af[2];
#pragma unroll
            for (int mi = 0; mi < 2; mi++)
                af[mi] = *(const bhalf8*)(Alds + (wm * 32 + mi * 16 + lm) * 72 + ks * 32 + lq * 8);
#pragma unroll
            for (int nt = 0; nt < 4; nt++) {
                bhalf8 bf = *(const bhalf8*)(Blds + (wn * 64 + nt * 16 + lm) * 72 + ks * 32 + lq * 8);
#pragma unroll
                for (int mi = 0; mi < 2; mi++)
                    acc[mi][nt] = __builtin_amdgcn_mfma_f32_16x16x32_bf16(af[mi], bf, acc[mi][nt], 0, 0, 0);
            }
        }
        __syncthreads();
    }
    int wsel = n0 / 768;
    int nb = n0 % 768;
    if (wsel == 2) {
        // V: bf16, transposed layout vt[((b*12+h)*64+d)*256 + q]
#pragma unroll
        for (int mi = 0; mi < 2; mi++)
#pragma unroll
            for (int nt = 0; nt < 4; nt++)
#pragma unroll
                for (int r = 0; r < 4; r++) {
                    int row = m0 + wm * 32 + mi * 16 + lq * 4 + r;
                    int col = nb + wn * 64 + nt * 16 + lm;
                    int hh = col >> 6, d = col & 63;
                    int b = row >> 8, qn = row & 255;
                    float val = acc[mi][nt][r] + bv[col];
                    vt[(((size_t)b * HEADS + hh) * Dd + d) * Nn + qn] = f2bf(val);
                }
    } else {
        const float* bias = (wsel == 0) ? bq : bk;
        float* dst = (wsel == 0) ? qs : kk;
        float scale = (wsel == 0) ? 0.125f : 1.0f;
#pragma unroll
        for (int mi = 0; mi < 2; mi++)
#pragma unroll
            for (int nt = 0; nt < 4; nt++)
#pragma unroll
                for (int r = 0; r < 4; r++) {
                    int row = m0 + wm * 32 + mi * 16 + lq * 4 + r;
                    int col = nb + wn * 64 + nt * 16 + lm;
                    int hh = col >> 6, d = col & 63;
                    int b = row >> 8, qn = row & 255;
                    float val = (acc[mi][nt][r] + bias[col]) * scale;
                    dst[(((size_t)b * HEADS + hh) * Nn + qn) * Dd + d] = val;
                }
    }
}

// ---------------- K2: content scores + bias, MFMA ----------------
__global__ __launch_bounds__(256) void k_scores(const float* __restrict__ qs,
                                                const float* __restrict__ kk,
                                                const float* __restrict__ bias,
                                                float* __restrict__ wg) {
    __shared__ __align__(16) unsigned short Alds[64 * 72];
    __shared__ __align__(16) unsigned short Blds[64 * 72];
    int tid = threadIdx.x;
    int bh = blockIdx.z;
    int m0 = blockIdx.y * 64;
    int n0 = blockIdx.x * 64;
    int w = tid >> 6, lane = tid & 63, lm = lane & 15, lq = lane >> 4;
    const float* Abase = qs + ((size_t)bh * Nn + m0) * Dd;
    const float* Bbase = kk + ((size_t)bh * Nn + n0) * Dd;
#pragma unroll
    for (int t = 0; t < 4; t++) {
        int c = t * 256 + tid;
        int row = c >> 4, cc = c & 15;
        float4 va = *(const float4*)(Abase + (size_t)row * 64 + cc * 4);
        uint2 ua;
        ua.x = (unsigned)f2bf(va.x) | ((unsigned)f2bf(va.y) << 16);
        ua.y = (unsigned)f2bf(va.z) | ((unsigned)f2bf(va.w) << 16);
        *(uint2*)(Alds + row * 72 + cc * 4) = ua;
        float4 vb = *(const float4*)(Bbase + (size_t)row * 64 + cc * 4);
        uint2 ub;
        ub.x = (unsigned)f2bf(vb.x) | ((unsigned)f2bf(vb.y) << 16);
        ub.y = (unsigned)f2bf(vb.z) | ((unsigned)f2bf(vb.w) << 16);
        *(uint2*)(Blds + row * 72 + cc * 4) = ub;
    }
    __syncthreads();
    f32x4 acc[4];
#pragma unroll
    for (int i = 0; i < 4; i++) acc[i] = (f32x4){0.f, 0.f, 0.f, 0.f};
#pragma unroll
    for (int ks = 0; ks < 2; ks++) {
        bhalf8 af = *(const bhalf8*)(Alds + (w * 16 + lm) * 72 + ks * 32 + lq * 8);
#pragma unroll
        for (int nt = 0; nt < 4; nt++) {
            bhalf8 bf = *(const bhalf8*)(Blds + (nt * 16 + lm) * 72 + ks * 32 + lq * 8);
            acc[nt] = __builtin_amdgcn_mfma_f32_16x16x32_bf16(af, bf, acc[nt], 0, 0, 0);
        }
    }
#pragma unroll
    for (int nt = 0; nt < 4; nt++)
#pragma unroll
        for (int r = 0; r < 4; r++) {
            int row = m0 + w * 16 + lq * 4 + r;
            int col = n0 + nt * 16 + lm;
            size_t idx = ((size_t)bh * Nn + row) * Nn + col;
            wg[idx] = acc[nt][r] + bias[idx];
        }
}

// ---------------- K4 (fused, 512 threads / 8 waves): path LN + struct proj + scores + softmax + struct out ----
// One block per (b,q). Wave w owns path/k rows [32w, 32w+32).
// R6 post-mortem: resident-block count is the dominant lever (3 blocks=160us, 2 blocks=211us).
// This version: XOR-swizzled unpadded LDS (SK [256][64], SVT [64][256], A2 [16][256]) ->
// 40960 B total -> 4 blocks/CU; redm/reds alias A2's first 1 KB (extra barrier closes the race);
// __launch_bounds__(512,4) caps VGPR at 64 (R4's register structure needs only 60).
__global__ __launch_bounds__(512, 4) void k_attn(const float* __restrict__ qs,
                                                 const float* __restrict__ paths,
                                                 const unsigned short* __restrict__ Wskvt, // [128 n][128 k] n-major, g-folded
                                                 const float* __restrict__ bskv2,          // [128] folded bias
                                                 const float* __restrict__ wg,             // fp32 content scores (in)
                                                 unsigned short* __restrict__ wgbf,        // bf16 probs (out)
                                                 float* __restrict__ attn) {
    __shared__ __align__(16) unsigned short SKbuf[256 * 64];   // SK [256][64] swizzled; aliased as SVT [64][256]
    __shared__ __align__(16) unsigned short A2buf[16 * 256];   // probs [16][256] swizzled; first 1KB = redm/reds
    unsigned short* SVT = SKbuf;
    float* redm = (float*)A2buf;          // [16][8]  (512 B)
    float* reds = ((float*)A2buf) + 128;  // [16][8]  (512 B)

    int tid = threadIdx.x;
    int bq = blockIdx.x;
    int b = bq >> 8, q = bq & 255;
    int w = tid >> 6, lane = tid & 63, lm = lane & 15, lq = lane >> 4;

    const float* ppath = paths + (size_t)bq * (256 * 128);

    // ---- Phase A: LN in registers, build bf16 A-fragments for rows [32w, 32w+32) ----
    bhalf8 afr[2][4];
#pragma unroll
    for (int mi = 0; mi < 2; mi++) {
        int R = w * 32 + mi * 16 + lm;
        const float* pr = ppath + (size_t)R * 128;
        float x[32];
#pragma unroll
        for (int ks = 0; ks < 4; ks++) {
            float4 a = *(const float4*)(pr + ks * 32 + lq * 8);
            float4 c = *(const float4*)(pr + ks * 32 + lq * 8 + 4);
            x[ks * 8 + 0] = a.x; x[ks * 8 + 1] = a.y; x[ks * 8 + 2] = a.z; x[ks * 8 + 3] = a.w;
            x[ks * 8 + 4] = c.x; x[ks * 8 + 5] = c.y; x[ks * 8 + 6] = c.z; x[ks * 8 + 7] = c.w;
        }
        float s = 0.f, s2 = 0.f;
#pragma unroll
        for (int i = 0; i < 32; i++) { s += x[i]; s2 += x[i] * x[i]; }
        s  += __shfl_xor(s, 16);  s2 += __shfl_xor(s2, 16);
        s  += __shfl_xor(s, 32);  s2 += __shfl_xor(s2, 32);
        float mu = s * (1.f / 128.f);
        float var = s2 * (1.f / 128.f) - mu * mu;
        float rs = rsqrtf(var + EPSf);
#pragma unroll
        for (int ks = 0; ks < 4; ks++) {
            bhalf8 t;
#pragma unroll
            for (int j = 0; j < 8; j++)
                t[j] = (short)f2bf((x[ks * 8 + j] - mu) * rs);
            afr[mi][ks] = t;
        }
    }

    // ---- Phase B1: SK pass (Wskvt rows 0..63), write straight to LDS (swizzled) ----
    {
        f32x4 acc[2][4];
#pragma unroll
        for (int i = 0; i < 2; i++)
#pragma unroll
            for (int j = 0; j < 4; j++) acc[i][j] = (f32x4){0.f, 0.f, 0.f, 0.f};
#pragma unroll
        for (int ks = 0; ks < 4; ks++) {
#pragma unroll
            for (int nt = 0; nt < 4; nt++) {
                bhalf8 bf = *(const bhalf8*)(Wskvt + (size_t)(nt * 16 + lm) * 128 + ks * 32 + lq * 8);
#pragma unroll
                for (int mi = 0; mi < 2; mi++)
                    acc[mi][nt] = __builtin_amdgcn_mfma_f32_16x16x32_bf16(afr[mi][ks], bf, acc[mi][nt], 0, 0, 0);
            }
        }
#pragma unroll
        for (int mi = 0; mi < 2; mi++)
#pragma unroll
            for (int nt = 0; nt < 4; nt++) {
                int col = nt * 16 + lm;
                float bb = bskv2[col];
#pragma unroll
                for (int rr = 0; rr < 4; rr++) {
                    int R2 = w * 32 + mi * 16 + lq * 4 + rr;
                    SKbuf[R2 * 64 + swz(R2, col)] = f2bf(acc[mi][nt][rr] + bb);
                }
            }
    }

    // ---- Phase B2: SV pass (Wskvt rows 64..127), keep in registers ----
    f32x4 accSV[2][4];
#pragma unroll
    for (int i = 0; i < 2; i++)
#pragma unroll
        for (int j = 0; j < 4; j++) accSV[i][j] = (f32x4){0.f, 0.f, 0.f, 0.f};
#pragma unroll
    for (int ks = 0; ks < 4; ks++) {
#pragma unroll
        for (int nt = 0; nt < 4; nt++) {
            bhalf8 bf = *(const bhalf8*)(Wskvt + (size_t)(64 + nt * 16 + lm) * 128 + ks * 32 + lq * 8);
#pragma unroll
            for (int mi = 0; mi < 2; mi++)
                accSV[mi][nt] = __builtin_amdgcn_mfma_f32_16x16x32_bf16(afr[mi][ks], bf, accSV[mi][nt], 0, 0, 0);
        }
    }

    // NOTE: no barrier here. MFMA1 wave w reads only SK rows [32w,32w+32) which wave w itself
    // wrote in B1; same-wave LDS ops execute in order. Cross-wave hazards start at the SVT
    // overwrite, which is guarded by the barrier below.

    // ---- Q fragments for MFMA1 (loaded late to keep them out of the proj live range) ----
    bhalf8 af1[2];
    {
        bhalf8 z = (bhalf8){0, 0, 0, 0, 0, 0, 0, 0};
        af1[0] = z; af1[1] = z;
        if (lm < 12) {
            const float* qp = qs + (((size_t)b * HEADS + lm) * Nn + q) * Dd;
#pragma unroll
            for (int ks = 0; ks < 2; ks++) {
                float4 v0 = *(const float4*)(qp + ks * 32 + lq * 8);
                float4 v1 = *(const float4*)(qp + ks * 32 + lq * 8 + 4);
                bhalf8 t;
                t[0] = (short)f2bf(v0.x); t[1] = (short)f2bf(v0.y);
                t[2] = (short)f2bf(v0.z); t[3] = (short)f2bf(v0.w);
                t[4] = (short)f2bf(v1.x); t[5] = (short)f2bf(v1.y);
                t[6] = (short)f2bf(v1.z); t[7] = (short)f2bf(v1.w);
                af1[ks] = t;
            }
        }
    }

    // ---- content scores from wg (post-proj placement; R4's 60-VGPR structure) ----
    size_t wbase = ((size_t)b * HEADS) * (Nn * Nn) + (size_t)q * Nn;
    float wgv[2][4];
#pragma unroll
    for (int nt = 0; nt < 2; nt++) {
        int col = w * 32 + nt * 16 + lm;
#pragma unroll
        for (int r = 0; r < 4; r++) {
            int row = lq * 4 + r;
            wgv[nt][r] = (row < 12) ? wg[wbase + (size_t)row * (Nn * Nn) + col] : 0.f;
        }
    }

    // ---- MFMA1: struct scores S[16 h][256 k] (wave w covers k in [32w, 32w+32)) + content scores ----
    f32x4 acc1[2];
#pragma unroll
    for (int i = 0; i < 2; i++) acc1[i] = (f32x4){0.f, 0.f, 0.f, 0.f};
#pragma unroll
    for (int ks = 0; ks < 2; ks++) {
#pragma unroll
        for (int nt = 0; nt < 2; nt++) {
            int row = w * 32 + nt * 16 + lm;
            bhalf8 bf = *(const bhalf8*)(SKbuf + row * 64 + swz(row, ks * 32 + lq * 8));
            acc1[nt] = __builtin_amdgcn_mfma_f32_16x16x32_bf16(af1[ks], bf, acc1[nt], 0, 0, 0);
        }
    }
    float S[2][4];
#pragma unroll
    for (int nt = 0; nt < 2; nt++)
#pragma unroll
        for (int r = 0; r < 4; r++) S[nt][r] = acc1[nt][r] + wgv[nt][r];

    // ---- SK region free after this barrier: write SV transposed SVT[64 d][256 k] (swizzled) ----
    __syncthreads();
#pragma unroll
    for (int mi = 0; mi < 2; mi++)
#pragma unroll
        for (int nt = 0; nt < 4; nt++) {
            int d = nt * 16 + lm;
            float bb = bskv2[64 + d];
#pragma unroll
            for (int rr = 0; rr < 4; rr++) {
                int R2 = w * 32 + mi * 16 + lq * 4 + rr;
                SVT[d * 256 + swz(d, R2)] = f2bf(accSV[mi][nt][rr] + bb);
            }
        }

    // ---- softmax over 256 cols per row (8 waves x 32 cols); redm/reds live in A2buf's head ----
    float m4[4];
#pragma unroll
    for (int r = 0; r < 4; r++)
        m4[r] = fmaxf(S[0][r], S[1][r]);
#pragma unroll
    for (int mk = 1; mk < 16; mk <<= 1)
#pragma unroll
        for (int r = 0; r < 4; r++) m4[r] = fmaxf(m4[r], __shfl_xor(m4[r], mk));
    if (lm == 0) {
#pragma unroll
        for (int r = 0; r < 4; r++) redm[(lq * 4 + r) * 8 + w] = m4[r];
    }
    __syncthreads();
    float rowmax[4];
#pragma unroll
    for (int r = 0; r < 4; r++) {
        int row = lq * 4 + r;
        float a = fmaxf(fmaxf(redm[row * 8 + 0], redm[row * 8 + 1]), fmaxf(redm[row * 8 + 2], redm[row * 8 + 3]));
        float c = fmaxf(fmaxf(redm[row * 8 + 4], redm[row * 8 + 5]), fmaxf(redm[row * 8 + 6], redm[row * 8 + 7]));
        rowmax[r] = fmaxf(a, c);
    }
    float P[2][4], psum[4];
#pragma unroll
    for (int r = 0; r < 4; r++) {
#pragma unroll
        for (int nt = 0; nt < 2; nt++) P[nt][r] = __expf(S[nt][r] - rowmax[r]);
        psum[r] = P[0][r] + P[1][r];
    }
#pragma unroll
    for (int mk = 1; mk < 16; mk <<= 1)
#pragma unroll
        for (int r = 0; r < 4; r++) psum[r] += __shfl_xor(psum[r], mk);
    if (lm == 0) {
#pragma unroll
        for (int r = 0; r < 4; r++) reds[(lq * 4 + r) * 8 + w] = psum[r];
    }
    __syncthreads();
    float inv[4];
#pragma unroll
    for (int r = 0; r < 4; r++) {
        int row = lq * 4 + r;
        float a = (reds[row * 8 + 0] + reds[row * 8 + 1]) + (reds[row * 8 + 2] + reds[row * 8 + 3]);
        float c = (reds[row * 8 + 4] + reds[row * 8 + 5]) + (reds[row * 8 + 6] + reds[row * 8 + 7]);
        inv[r] = 1.f / (a + c);
    }
    __syncthreads();   // all waves done reading redm/reds before A2 overwrites them
    // probs: bf16 into A2 (MFMA2 A-operand, swizzled) and into wgbf for K5
#pragma unroll
    for (int nt = 0; nt < 2; nt++)
#pragma unroll
        for (int r = 0; r < 4; r++) {
            int row = lq * 4 + r;
            int col = w * 32 + nt * 16 + lm;
            float pv = P[nt][r] * inv[r];
            unsigned short pb = f2bf(pv);
            A2buf[row * 256 + swz(row, col)] = pb;
            if (row < 12) wgbf[wbase + (size_t)row * (Nn * Nn) + col] = pb;
        }
    __syncthreads();

    // ---- MFMA2 (waves 0..3): O[16 h][64 d] = P[16,256] @ SV[256,64]; wave w -> d-tile w*16 ----
    if (w < 4) {
        f32x4 acc2 = (f32x4){0.f, 0.f, 0.f, 0.f};
#pragma unroll
        for (int ks = 0; ks < 8; ks++) {
            bhalf8 af = *(const bhalf8*)(A2buf + lm * 256 + swz(lm, ks * 32 + lq * 8));
            int vrow = w * 16 + lm;
            bhalf8 bf = *(const bhalf8*)(SVT + vrow * 256 + swz(vrow, ks * 32 + lq * 8));
            acc2 = __builtin_amdgcn_mfma_f32_16x16x32_bf16(af, bf, acc2, 0, 0, 0);
        }
#pragma unroll
        for (int r = 0; r < 4; r++) {
            int row = lq * 4 + r;
            if (row < 12) attn[(size_t)bq * Hh + row * 64 + w * 16 + lm] = acc2[r];
        }
    }
}

// ---------------- K5: content out = P(bf16) @ V(bf16), MFMA, accumulate into attn ----------------
__global__ __launch_bounds__(256) void k_ctxout(const unsigned short* __restrict__ wgbf, // [b,h,q,k] bf16
                                                const unsigned short* __restrict__ vt,   // [b,h,d,k] bf16
                                                float* __restrict__ attn) {
    __shared__ __align__(16) unsigned short Alds[64 * 72];
    __shared__ __align__(16) unsigned short Blds[64 * 72];
    int tid = threadIdx.x;
    int bh = blockIdx.y;
    int m0 = blockIdx.x * 64;
    int b = bh / 12, h = bh % 12;
    int w = tid >> 6, lane = tid & 63, lm = lane & 15, lq = lane >> 4;
    f32x4 acc[4];
#pragma unroll
    for (int i = 0; i < 4; i++) acc[i] = (f32x4){0.f, 0.f, 0.f, 0.f};
    const unsigned short* Abase = wgbf + ((size_t)bh * Nn + m0) * Nn;
    const unsigned short* Bbase = vt + (size_t)bh * Dd * Nn;
    for (int kt = 0; kt < 256; kt += 64) {
#pragma unroll
        for (int t = 0; t < 2; t++) {
            int c = t * 256 + tid;
            int row = c >> 3, kc = c & 7;
            *(uint4*)(Alds + row * 72 + kc * 8) = *(const uint4*)(Abase + (size_t)row * Nn + kt + kc * 8);
            *(uint4*)(Blds + row * 72 + kc * 8) = *(const uint4*)(Bbase + (size_t)row * Nn + kt + kc * 8);
        }
        __syncthreads();
#pragma unroll
        for (int ks = 0; ks < 2; ks++) {
            bhalf8 af = *(const bhalf8*)(Alds + (w * 16 + lm) * 72 + ks * 32 + lq * 8);
#pragma unroll
            for (int nt = 0; nt < 4; nt++) {
                bhalf8 bf = *(const bhalf8*)(Blds + (nt * 16 + lm) * 72 + ks * 32 + lq * 8);
                acc[nt] = __builtin_amdgcn_mfma_f32_16x16x32_bf16(af, bf, acc[nt], 0, 0, 0);
            }
        }
        __syncthreads();
    }
#pragma unroll
    for (int nt = 0; nt < 4; nt++)
#pragma unroll
        for (int r = 0; r < 4; r++) {
            int row = m0 + w * 16 + lq * 4 + r;
            int col = nt * 16 + lm;
            size_t o = ((size_t)b * Nn + row) * Hh + h * 64 + col;
            attn[o] += acc[nt][r];
        }
}

// ---------------- K6: out projection + bias + relu + residual, MFMA ----------------
__global__ __launch_bounds__(256) void k_outproj(const float* __restrict__ attn,
                                                 const unsigned short* __restrict__ Wot, // [768][768] n-major
                                                 const float* __restrict__ bo,
                                                 const float* __restrict__ nodes,
                                                 float* __restrict__ tmp) {
    __shared__ __align__(16) unsigned short Alds[64 * 72];
    __shared__ __align__(16) unsigned short Blds[128 * 72];
    int tid = threadIdx.x;
    int m0 = blockIdx.y * 64;
    int n0 = blockIdx.x * 128;
    int w = tid >> 6, lane = tid & 63;
    int wm = w >> 1, wn = w & 1;
    int lm = lane & 15, lq = lane >> 4;
    f32x4 acc[2][4];
#pragma unroll
    for (int i = 0; i < 2; i++)
#pragma unroll
        for (int j = 0; j < 4; j++) acc[i][j] = (f32x4){0.f, 0.f, 0.f, 0.f};
    for (int kt = 0; kt < 768; kt += 64) {
#pragma unroll
        for (int t = 0; t < 4; t++) {
            int c = t * 256 + tid;
            int row = c >> 4, cc = c & 15;
            float4 v = *(const float4*)(attn + (size_t)(m0 + row) * 768 + kt + cc * 4);
            uint2 uu;
            uu.x = (unsigned)f2bf(v.x) | ((unsigned)f2bf(v.y) << 16);
            uu.y = (unsigned)f2bf(v.z) | ((unsigned)f2bf(v.w) << 16);
            *(uint2*)(Alds + row * 72 + cc * 4) = uu;
        }
#pragma unroll
        for (int t = 0; t < 4; t++) {
            int c = t * 256 + tid;
            int n = c >> 3, kc = c & 7;
            uint4 v = *(const uint4*)(Wot + (size_t)(n0 + n) * 768 + kt + kc * 8);
            *(uint4*)(Blds + n * 72 + kc * 8) = v;
        }
        __syncthreads();
#pragma unroll
        for (int ks = 0; ks < 2; ks++) {
            bhalf8 af[2];
#pragma unroll
            for (int mi = 0; mi < 2; mi++)
                af[mi] = *(const bhalf8*)(Alds + (wm * 32 + mi * 16 + lm) * 72 + ks * 32 + lq * 8);
#pragma unroll
            for (int nt = 0; nt < 4; nt++) {
                bhalf8 bf = *(const bhalf8*)(Blds + (wn * 64 + nt * 16 + lm) * 72 + ks * 32 + lq * 8);
#pragma unroll
                for (int mi = 0; mi < 2; mi++)
                    acc[mi][nt] = __builtin_amdgcn_mfma_f32_16x16x32_bf16(af[mi], bf, acc[mi][nt], 0, 0, 0);
            }
        }
        __syncthreads();
    }
#pragma unroll
    for (int mi = 0; mi < 2; mi++)
#pragma unroll
        for (int nt = 0; nt < 4; nt++)
#pragma unroll
            for (int r = 0; r < 4; r++) {
                int row = m0 + wm * 32 + mi * 16 + lq * 4 + r;
                int col = n0 + wn * 64 + nt * 16 + lm;
                float val = acc[mi][nt][r] + bo[col];
                val = fmaxf(val, 0.f) + nodes[(size_t)row * 768 + col];
                tmp[(size_t)row * 768 + col] = val;
            }
}

// ---------------- K7: final row LayerNorm ----------------
__global__ __launch_bounds__(256) void k_finalln(const float* __restrict__ tmp,
                                                 const float* __restrict__ go,
                                                 const float* __restrict__ bout,
                                                 float* __restrict__ out) {
    __shared__ float rs1[4], rs2[4];
    int m = blockIdx.x, tid = threadIdx.x;
    int lane = tid & 63, wid = tid >> 6;
    const float* row = tmp + (size_t)m * 768;
    float x0 = row[tid], x1 = row[tid + 256], x2 = row[tid + 512];
    float s = x0 + x1 + x2;
    float s2 = x0 * x0 + x1 * x1 + x2 * x2;
#pragma unroll
    for (int mk = 32; mk; mk >>= 1) {
        s += __shfl_xor(s, mk);
        s2 += __shfl_xor(s2, mk);
    }
    if (lane == 0) { rs1[wid] = s; rs2[wid] = s2; }
    __syncthreads();
    s = rs1[0] + rs1[1] + rs1[2] + rs1[3];
    s2 = rs2[0] + rs2[1] + rs2[2] + rs2[3];
    float mu = s * (1.f / 768.f);
    float var = s2 * (1.f / 768.f) - mu * mu;
    float rstd = rsqrtf(var + EPSf);
    float* orow = out + (size_t)m * 768;
    orow[tid] = (x0 - mu) * rstd * go[tid] + bout[tid];
    orow[tid + 256] = (x1 - mu) * rstd * go[tid + 256] + bout[tid + 256];
    orow[tid + 512] = (x2 - mu) * rstd * go[tid + 512] + bout[tid + 512];
}

extern "C" void kernel_launch(void* const* d_in, const int* in_sizes, int n_in,
                              void* d_out, int out_size, void* d_ws, size_t ws_size,
                              hipStream_t stream) {
    const float* nodes = (const float*)d_in[0];
    const float* bias  = (const float*)d_in[1];
    const float* paths = (const float*)d_in[2];
    const float* Wq = (const float*)d_in[3];  const float* bq  = (const float*)d_in[4];
    const float* Wk = (const float*)d_in[5];  const float* bk  = (const float*)d_in[6];
    const float* Wv = (const float*)d_in[7];  const float* bv  = (const float*)d_in[8];
    const float* Wsk = (const float*)d_in[9]; const float* bsk = (const float*)d_in[10];
    const float* Wsv = (const float*)d_in[11];const float* bsv = (const float*)d_in[12];
    const float* Wo = (const float*)d_in[13]; const float* bo  = (const float*)d_in[14];
    const float* gp = (const float*)d_in[15]; const float* bp  = (const float*)d_in[16];
    const float* go = (const float*)d_in[17]; const float* bout= (const float*)d_in[18];
    float* out = (float*)d_out;

    char* ws = (char*)d_ws;
    size_t off = 0;
    auto carve = [&](size_t bytes) -> char* {
        char* p = ws + off;
        off += (bytes + 255) & ~(size_t)255;
        return p;
    };
    float* qs   = (float*)carve((size_t)Bb * HEADS * Nn * Dd * 4);
    float* kk   = (float*)carve((size_t)Bb * HEADS * Nn * Dd * 4);
    unsigned short* vt = (unsigned short*)carve((size_t)Bb * HEADS * Dd * Nn * 2);
    float* wg   = (float*)carve((size_t)Bb * HEADS * Nn * Nn * 4);
    unsigned short* wgbf = (unsigned short*)carve((size_t)Bb * HEADS * Nn * Nn * 2);
    float* attn = (float*)carve((size_t)Bb * Nn * Hh * 4);
    float* tmp  = (float*)carve((size_t)Bb * Nn * Hh * 4);
    unsigned short* Wqkvt = (unsigned short*)carve((size_t)3 * 768 * 768 * 2);
    unsigned short* Wot   = (unsigned short*)carve((size_t)768 * 768 * 2);
    unsigned short* Wskvt = (unsigned short*)carve((size_t)128 * 128 * 2);
    float* bskv2 = (float*)carve(128 * 4);
    (void)ws_size; (void)in_sizes; (void)n_in; (void)out_size;

    // K0: weight transposes (fp32 -> bf16, n-major); g_path folded into Wskvt; bias' = bp@W + bskv
    hipLaunchKernelGGL(k_transpose4, dim3(24, 24, 4), dim3(256), 0, stream,
                       Wq, Wk, Wv, Wo,
                       Wqkvt, Wqkvt + (size_t)768 * 768, Wqkvt + (size_t)2 * 768 * 768, Wot);
    hipLaunchKernelGGL(k_transpose_small, dim3(2, 4, 2), dim3(256), 0, stream,
                       Wsk, Wsv, gp, Wskvt, Wskvt + (size_t)64 * 128);
    hipLaunchKernelGGL(k_prep_bias, dim3(1), dim3(128), 0, stream,
                       Wsk, Wsv, bp, bsk, bsv, bskv2);

    // K1: QKV (V -> bf16 transposed vt)
    hipLaunchKernelGGL(k_qkv, dim3(18, 32), dim3(256), 0, stream, nodes, Wqkvt, bq, bk, bv, qs, kk, vt);
    // K2: content scores + bias (fp32)
    hipLaunchKernelGGL(k_scores, dim3(4, 4, 96), dim3(256), 0, stream, qs, kk, bias, wg);
    // K4 (fused, 512 thr): path LN + struct proj + struct scores + softmax + struct out
    hipLaunchKernelGGL(k_attn, dim3(2048), dim3(512), 0, stream, qs, paths, Wskvt, bskv2, wg, wgbf, attn);
    // K5: content out accumulate (MFMA bf16)
    hipLaunchKernelGGL(k_ctxout, dim3(4, 96), dim3(256), 0, stream, wgbf, vt, attn);
    // K6: output projection + relu + residual
    hipLaunchKernelGGL(k_outproj, dim3(6, 32), dim3(256), 0, stream, attn, Wot, bo, nodes, tmp);
    // K7: final layernorm
    hipLaunchKernelGGL(k_finalln, dim3(2048), dim3(256), 0, stream, tmp, go, bout, out);
}

// Round 9
// 558.435 us; speedup vs baseline: 1.0951x; 1.0002x over previous
//
#include <hip/hip_runtime.h>
#include <stdint.h>

#define Bb 8
#define Nn 256
#define Hh 768
#define Pp 128
#define HEADS 12
#define Dd 64
#define EPSf 1e-5f

typedef __attribute__((ext_vector_type(8))) short bhalf8;   // 8 bf16 (4 VGPRs)
typedef __attribute__((ext_vector_type(4))) float f32x4;

__device__ __forceinline__ unsigned short f2bf(float f) {
    union { float f; unsigned u; } v; v.f = f;
    unsigned r = v.u + 0x7FFFu + ((v.u >> 16) & 1u);
    return (unsigned short)(r >> 16);
}

// XOR swizzle on ushort column index: flips ushort-index bits 3..5 with row bits 0..2.
// Applied identically on write and read -> bijective; 8-aligned runs stay contiguous.
__device__ __forceinline__ int swz(int row, int colUs) {
    return colUs ^ ((row & 7) << 3);
}

// ---------------- K0a: 4x transpose fp32 [768][768] -> bf16 n-major ----------------
__global__ __launch_bounds__(256) void k_transpose4(const float* __restrict__ a0, const float* __restrict__ a1,
                                                    const float* __restrict__ a2, const float* __restrict__ a3,
                                                    unsigned short* __restrict__ o0, unsigned short* __restrict__ o1,
                                                    unsigned short* __restrict__ o2, unsigned short* __restrict__ o3) {
    __shared__ float tile[32][33];
    int z = blockIdx.z;
    const float* in = (z == 0) ? a0 : (z == 1) ? a1 : (z == 2) ? a2 : a3;
    unsigned short* out = (z == 0) ? o0 : (z == 1) ? o1 : (z == 2) ? o2 : o3;
    const int R = 768, C = 768;
    int c0 = blockIdx.x * 32, r0 = blockIdx.y * 32;
    int tx = threadIdx.x & 31, ty = threadIdx.x >> 5;
    for (int i = ty; i < 32; i += 8)
        tile[i][tx] = in[(size_t)(r0 + i) * C + c0 + tx];
    __syncthreads();
    for (int i = ty; i < 32; i += 8)
        out[(size_t)(c0 + i) * R + r0 + tx] = f2bf(tile[tx][i]);
}

// ---------------- K0b: 2x transpose fp32 [128][64] -> bf16 [64][128], folding g_path ----------------
__global__ __launch_bounds__(256) void k_transpose_small(const float* __restrict__ a0, const float* __restrict__ a1,
                                                         const float* __restrict__ gp,
                                                         unsigned short* __restrict__ o0, unsigned short* __restrict__ o1) {
    __shared__ float tile[32][33];
    int z = blockIdx.z;
    const float* in = (z == 0) ? a0 : a1;
    unsigned short* out = (z == 0) ? o0 : o1;
    const int R = 128, C = 64;
    int c0 = blockIdx.x * 32, r0 = blockIdx.y * 32;
    int tx = threadIdx.x & 31, ty = threadIdx.x >> 5;
    for (int i = ty; i < 32; i += 8)
        tile[i][tx] = in[(size_t)(r0 + i) * C + c0 + tx];
    __syncthreads();
    float g = gp[r0 + tx];   // input row index (p) = r0+tx after transpose read
    for (int i = ty; i < 32; i += 8)
        out[(size_t)(c0 + i) * R + r0 + tx] = f2bf(tile[tx][i] * g);
}

// ---------------- K0c: bskv2[d] = b_path @ W + bias (struct bias folding) ----------------
__global__ __launch_bounds__(128) void k_prep_bias(const float* __restrict__ Wsk, const float* __restrict__ Wsv,
                                                   const float* __restrict__ bp,
                                                   const float* __restrict__ bsk, const float* __restrict__ bsv,
                                                   float* __restrict__ bskv2) {
    int d = threadIdx.x;          // 0..127
    const float* W = (d < 64) ? Wsk : Wsv;
    int dd = d & 63;
    float s = (d < 64) ? bsk[dd] : bsv[dd];
    for (int p2 = 0; p2 < 128; p2++) s += bp[p2] * W[p2 * 64 + dd];
    bskv2[d] = s;
}

// ---------------- K1: QKV projection, MFMA bf16. V written bf16 transposed vt[b,h,d,k] ----------------
__global__ __launch_bounds__(256) void k_qkv(const float* __restrict__ nodes,
                                             const unsigned short* __restrict__ Wt, // [2304][768] n-major
                                             const float* __restrict__ bq, const float* __restrict__ bk,
                                             const float* __restrict__ bv,
                                             float* __restrict__ qs, float* __restrict__ kk,
                                             unsigned short* __restrict__ vt) {
    __shared__ __align__(16) unsigned short Alds[64 * 72];
    __shared__ __align__(16) unsigned short Blds[128 * 72];
    int tid = threadIdx.x;
    int m0 = blockIdx.y * 64;
    int n0 = blockIdx.x * 128;
    int w = tid >> 6, lane = tid & 63;
    int wm = w >> 1, wn = w & 1;
    int lm = lane & 15, lq = lane >> 4;
    f32x4 acc[2][4];
#pragma unroll
    for (int i = 0; i < 2; i++)
#pragma unroll
        for (int j = 0; j < 4; j++) acc[i][j] = (f32x4){0.f, 0.f, 0.f, 0.f};

    for (int kt = 0; kt < 768; kt += 64) {
#pragma unroll
        for (int t = 0; t < 4; t++) {  // A: 64x64 fp32 -> bf16
            int c = t * 256 + tid;
            int row = c >> 4, cc = c & 15;
            float4 v = *(const float4*)(nodes + (size_t)(m0 + row) * 768 + kt + cc * 4);
            uint2 uu;
            uu.x = (unsigned)f2bf(v.x) | ((unsigned)f2bf(v.y) << 16);
            uu.y = (unsigned)f2bf(v.z) | ((unsigned)f2bf(v.w) << 16);
            *(uint2*)(Alds + row * 72 + cc * 4) = uu;
        }
#pragma unroll
        for (int t = 0; t < 4; t++) {  // B: 128x64 bf16
            int c = t * 256 + tid;
            int n = c >> 3, kc = c & 7;
            uint4 v = *(const uint4*)(Wt + (size_t)(n0 + n) * 768 + kt + kc * 8);
            *(uint4*)(Blds + n * 72 + kc * 8) = v;
        }
        __syncthreads();
#pragma unroll
        for (int ks = 0; ks < 2; ks++) {
            bhalf8 af[2];
#pragma unroll
            for (int mi = 0; mi < 2; mi++)
                af[mi] = *(const bhalf8*)(Alds + (wm * 32 + mi * 16 + lm) * 72 + ks * 32 + lq * 8);
#pragma unroll
            for (int nt = 0; nt < 4; nt++) {
                bhalf8 bf = *(const bhalf8*)(Blds + (wn * 64 + nt * 16 + lm) * 72 + ks * 32 + lq * 8);
#pragma unroll
                for (int mi = 0; mi < 2; mi++)
                    acc[mi][nt] = __builtin_amdgcn_mfma_f32_16x16x32_bf16(af[mi], bf, acc[mi][nt], 0, 0, 0);
            }
        }
        __syncthreads();
    }
    int wsel = n0 / 768;
    int nb = n0 % 768;
    if (wsel == 2) {
        // V: bf16, transposed layout vt[((b*12+h)*64+d)*256 + q]
#pragma unroll
        for (int mi = 0; mi < 2; mi++)
#pragma unroll
            for (int nt = 0; nt < 4; nt++)
#pragma unroll
                for (int r = 0; r < 4; r++) {
                    int row = m0 + wm * 32 + mi * 16 + lq * 4 + r;
                    int col = nb + wn * 64 + nt * 16 + lm;
                    int hh = col >> 6, d = col & 63;
                    int b = row >> 8, qn = row & 255;
                    float val = acc[mi][nt][r] + bv[col];
                    vt[(((size_t)b * HEADS + hh) * Dd + d) * Nn + qn] = f2bf(val);
                }
    } else {
        const float* bias = (wsel == 0) ? bq : bk;
        float* dst = (wsel == 0) ? qs : kk;
        float scale = (wsel == 0) ? 0.125f : 1.0f;
#pragma unroll
        for (int mi = 0; mi < 2; mi++)
#pragma unroll
            for (int nt = 0; nt < 4; nt++)
#pragma unroll
                for (int r = 0; r < 4; r++) {
                    int row = m0 + wm * 32 + mi * 16 + lq * 4 + r;
                    int col = nb + wn * 64 + nt * 16 + lm;
                    int hh = col >> 6, d = col & 63;
                    int b = row >> 8, qn = row & 255;
                    float val = (acc[mi][nt][r] + bias[col]) * scale;
                    dst[(((size_t)b * HEADS + hh) * Nn + qn) * Dd + d] = val;
                }
    }
}

// ---------------- K2: content scores + bias, MFMA ----------------
__global__ __launch_bounds__(256) void k_scores(const float* __restrict__ qs,
                                                const float* __restrict__ kk,
                                                const float* __restrict__ bias,
                                                float* __restrict__ wg) {
    __shared__ __align__(16) unsigned short Alds[64 * 72];
    __shared__ __align__(16) unsigned short Blds[64 * 72];
    int tid = threadIdx.x;
    int bh = blockIdx.z;
    int m0 = blockIdx.y * 64;
    int n0 = blockIdx.x * 64;
    int w = tid >> 6, lane = tid & 63, lm = lane & 15, lq = lane >> 4;
    const float* Abase = qs + ((size_t)bh * Nn + m0) * Dd;
    const float* Bbase = kk + ((size_t)bh * Nn + n0) * Dd;
#pragma unroll
    for (int t = 0; t < 4; t++) {
        int c = t * 256 + tid;
        int row = c >> 4, cc = c & 15;
        float4 va = *(const float4*)(Abase + (size_t)row * 64 + cc * 4);
        uint2 ua;
        ua.x = (unsigned)f2bf(va.x) | ((unsigned)f2bf(va.y) << 16);
        ua.y = (unsigned)f2bf(va.z) | ((unsigned)f2bf(va.w) << 16);
        *(uint2*)(Alds + row * 72 + cc * 4) = ua;
        float4 vb = *(const float4*)(Bbase + (size_t)row * 64 + cc * 4);
        uint2 ub;
        ub.x = (unsigned)f2bf(vb.x) | ((unsigned)f2bf(vb.y) << 16);
        ub.y = (unsigned)f2bf(vb.z) | ((unsigned)f2bf(vb.w) << 16);
        *(uint2*)(Blds + row * 72 + cc * 4) = ub;
    }
    __syncthreads();
    f32x4 acc[4];
#pragma unroll
    for (int i = 0; i < 4; i++) acc[i] = (f32x4){0.f, 0.f, 0.f, 0.f};
#pragma unroll
    for (int ks = 0; ks < 2; ks++) {
        bhalf8 af = *(const bhalf8*)(Alds + (w * 16 + lm) * 72 + ks * 32 + lq * 8);
#pragma unroll
        for (int nt = 0; nt < 4; nt++) {
            bhalf8 bf = *(const bhalf8*)(Blds + (nt * 16 + lm) * 72 + ks * 32 + lq * 8);
            acc[nt] = __builtin_amdgcn_mfma_f32_16x16x32_bf16(af, bf, acc[nt], 0, 0, 0);
        }
    }
#pragma unroll
    for (int nt = 0; nt < 4; nt++)
#pragma unroll
        for (int r = 0; r < 4; r++) {
            int row = m0 + w * 16 + lq * 4 + r;
            int col = n0 + nt * 16 + lm;
            size_t idx = ((size_t)bh * Nn + row) * Nn + col;
            wg[idx] = acc[nt][r] + bias[idx];
        }
}

// ---------------- K4 (fused, 512 threads / 8 waves): path LN + struct proj + scores + softmax + struct out ----
// One block per (b,q). Wave w owns path/k rows [32w, 32w+32).
// R7 post-mortem: 40,960 B LDS = exactly 4x160KiB -> 4th block likely rejected (dur tied R4).
// This version: 32 KB shared region (SK [256][64]swz; repartitioned after MFMA1 as A2 [16][256]swz
// + SVT-HALF [32][256]swz, consumed in two d-halves) + 1 KB reduction buffer = 33,792 B total ->
// comfortably 4 blocks/CU (the 32-wave/CU cap). VGPR structure identical to R7 (late wgv/af1).
__global__ __launch_bounds__(512, 4) void k_attn(const float* __restrict__ qs,
                                                 const float* __restrict__ paths,
                                                 const unsigned short* __restrict__ Wskvt, // [128 n][128 k] n-major, g-folded
                                                 const float* __restrict__ bskv2,          // [128] folded bias
                                                 const float* __restrict__ wg,             // fp32 content scores (in)
                                                 unsigned short* __restrict__ wgbf,        // bf16 probs (out)
                                                 float* __restrict__ attn) {
    __shared__ __align__(16) unsigned short SH[256 * 64];  // 32 KB: SK phase, then A2 + SVT-half
    __shared__ float red[256];                             // redm [16][8] @0, reds [16][8] @128
    unsigned short* A2 = SH;            // [16][256] swizzled (8 KB)
    unsigned short* SVTh = SH + 4096;   // [32][256] swizzled (16 KB), two d-halves sequentially
    float* redm = red;
    float* reds = red + 128;

    int tid = threadIdx.x;
    int bq = blockIdx.x;
    int b = bq >> 8, q = bq & 255;
    int w = tid >> 6, lane = tid & 63, lm = lane & 15, lq = lane >> 4;

    const float* ppath = paths + (size_t)bq * (256 * 128);

    // ---- Phase A: LN in registers, build bf16 A-fragments for rows [32w, 32w+32) ----
    bhalf8 afr[2][4];
#pragma unroll
    for (int mi = 0; mi < 2; mi++) {
        int R = w * 32 + mi * 16 + lm;
        const float* pr = ppath + (size_t)R * 128;
        float x[32];
#pragma unroll
        for (int ks = 0; ks < 4; ks++) {
            float4 a = *(const float4*)(pr + ks * 32 + lq * 8);
            float4 c = *(const float4*)(pr + ks * 32 + lq * 8 + 4);
            x[ks * 8 + 0] = a.x; x[ks * 8 + 1] = a.y; x[ks * 8 + 2] = a.z; x[ks * 8 + 3] = a.w;
            x[ks * 8 + 4] = c.x; x[ks * 8 + 5] = c.y; x[ks * 8 + 6] = c.z; x[ks * 8 + 7] = c.w;
        }
        float s = 0.f, s2 = 0.f;
#pragma unroll
        for (int i = 0; i < 32; i++) { s += x[i]; s2 += x[i] * x[i]; }
        s  += __shfl_xor(s, 16);  s2 += __shfl_xor(s2, 16);
        s  += __shfl_xor(s, 32);  s2 += __shfl_xor(s2, 32);
        float mu = s * (1.f / 128.f);
        float var = s2 * (1.f / 128.f) - mu * mu;
        float rs = rsqrtf(var + EPSf);
#pragma unroll
        for (int ks = 0; ks < 4; ks++) {
            bhalf8 t;
#pragma unroll
            for (int j = 0; j < 8; j++)
                t[j] = (short)f2bf((x[ks * 8 + j] - mu) * rs);
            afr[mi][ks] = t;
        }
    }

    // ---- Phase B1: SK pass (Wskvt rows 0..63), write straight to LDS (swizzled) ----
    {
        f32x4 acc[2][4];
#pragma unroll
        for (int i = 0; i < 2; i++)
#pragma unroll
            for (int j = 0; j < 4; j++) acc[i][j] = (f32x4){0.f, 0.f, 0.f, 0.f};
#pragma unroll
        for (int ks = 0; ks < 4; ks++) {
#pragma unroll
            for (int nt = 0; nt < 4; nt++) {
                bhalf8 bf = *(const bhalf8*)(Wskvt + (size_t)(nt * 16 + lm) * 128 + ks * 32 + lq * 8);
#pragma unroll
                for (int mi = 0; mi < 2; mi++)
                    acc[mi][nt] = __builtin_amdgcn_mfma_f32_16x16x32_bf16(afr[mi][ks], bf, acc[mi][nt], 0, 0, 0);
            }
        }
#pragma unroll
        for (int mi = 0; mi < 2; mi++)
#pragma unroll
            for (int nt = 0; nt < 4; nt++) {
                int col = nt * 16 + lm;
                float bb = bskv2[col];
#pragma unroll
                for (int rr = 0; rr < 4; rr++) {
                    int R2 = w * 32 + mi * 16 + lq * 4 + rr;
                    SH[R2 * 64 + swz(R2, col)] = f2bf(acc[mi][nt][rr] + bb);
                }
            }
    }

    // ---- Phase B2: SV pass (Wskvt rows 64..127), keep in registers ----
    f32x4 accSV[2][4];
#pragma unroll
    for (int i = 0; i < 2; i++)
#pragma unroll
        for (int j = 0; j < 4; j++) accSV[i][j] = (f32x4){0.f, 0.f, 0.f, 0.f};
#pragma unroll
    for (int ks = 0; ks < 4; ks++) {
#pragma unroll
        for (int nt = 0; nt < 4; nt++) {
            bhalf8 bf = *(const bhalf8*)(Wskvt + (size_t)(64 + nt * 16 + lm) * 128 + ks * 32 + lq * 8);
#pragma unroll
            for (int mi = 0; mi < 2; mi++)
                accSV[mi][nt] = __builtin_amdgcn_mfma_f32_16x16x32_bf16(afr[mi][ks], bf, accSV[mi][nt], 0, 0, 0);
        }
    }

    // NOTE: no barrier here. MFMA1 wave w reads only SK rows [32w,32w+32) which wave w itself
    // wrote in B1; same-wave LDS ops execute in order.

    // ---- Q fragments for MFMA1 (loaded late to keep them out of the proj live range) ----
    bhalf8 af1[2];
    {
        bhalf8 z = (bhalf8){0, 0, 0, 0, 0, 0, 0, 0};
        af1[0] = z; af1[1] = z;
        if (lm < 12) {
            const float* qp = qs + (((size_t)b * HEADS + lm) * Nn + q) * Dd;
#pragma unroll
            for (int ks = 0; ks < 2; ks++) {
                float4 v0 = *(const float4*)(qp + ks * 32 + lq * 8);
                float4 v1 = *(const float4*)(qp + ks * 32 + lq * 8 + 4);
                bhalf8 t;
                t[0] = (short)f2bf(v0.x); t[1] = (short)f2bf(v0.y);
                t[2] = (short)f2bf(v0.z); t[3] = (short)f2bf(v0.w);
                t[4] = (short)f2bf(v1.x); t[5] = (short)f2bf(v1.y);
                t[6] = (short)f2bf(v1.z); t[7] = (short)f2bf(v1.w);
                af1[ks] = t;
            }
        }
    }

    // ---- content scores from wg (late placement; R4/R7 register structure) ----
    size_t wbase = ((size_t)b * HEADS) * (Nn * Nn) + (size_t)q * Nn;
    float wgv[2][4];
#pragma unroll
    for (int nt = 0; nt < 2; nt++) {
        int col = w * 32 + nt * 16 + lm;
#pragma unroll
        for (int r = 0; r < 4; r++) {
            int row = lq * 4 + r;
            wgv[nt][r] = (row < 12) ? wg[wbase + (size_t)row * (Nn * Nn) + col] : 0.f;
        }
    }

    // ---- MFMA1: struct scores S[16 h][256 k] (wave w covers k in [32w, 32w+32)) + content scores ----
    f32x4 acc1[2];
#pragma unroll
    for (int i = 0; i < 2; i++) acc1[i] = (f32x4){0.f, 0.f, 0.f, 0.f};
#pragma unroll
    for (int ks = 0; ks < 2; ks++) {
#pragma unroll
        for (int nt = 0; nt < 2; nt++) {
            int row = w * 32 + nt * 16 + lm;
            bhalf8 bf = *(const bhalf8*)(SH + row * 64 + swz(row, ks * 32 + lq * 8));
            acc1[nt] = __builtin_amdgcn_mfma_f32_16x16x32_bf16(af1[ks], bf, acc1[nt], 0, 0, 0);
        }
    }
    float S[2][4];
#pragma unroll
    for (int nt = 0; nt < 2; nt++)
#pragma unroll
        for (int r = 0; r < 4; r++) S[nt][r] = acc1[nt][r] + wgv[nt][r];

    // ---- SK region free after this barrier; repartition as A2 + SVTh ----
    __syncthreads();

    // SVT half 1: d in [0,32)  (accSV nt 0..1)
#pragma unroll
    for (int mi = 0; mi < 2; mi++)
#pragma unroll
        for (int nt = 0; nt < 2; nt++) {
            int d = nt * 16 + lm;
            float bb = bskv2[64 + d];
#pragma unroll
            for (int rr = 0; rr < 4; rr++) {
                int R2 = w * 32 + mi * 16 + lq * 4 + rr;
                SVTh[d * 256 + swz(d, R2)] = f2bf(accSV[mi][nt][rr] + bb);
            }
        }

    // ---- softmax over 256 cols per row (8 waves x 32 cols) ----
    float m4[4];
#pragma unroll
    for (int r = 0; r < 4; r++)
        m4[r] = fmaxf(S[0][r], S[1][r]);
#pragma unroll
    for (int mk = 1; mk < 16; mk <<= 1)
#pragma unroll
        for (int r = 0; r < 4; r++) m4[r] = fmaxf(m4[r], __shfl_xor(m4[r], mk));
    if (lm == 0) {
#pragma unroll
        for (int r = 0; r < 4; r++) redm[(lq * 4 + r) * 8 + w] = m4[r];
    }
    __syncthreads();
    float rowmax[4];
#pragma unroll
    for (int r = 0; r < 4; r++) {
        int row = lq * 4 + r;
        float a = fmaxf(fmaxf(redm[row * 8 + 0], redm[row * 8 + 1]), fmaxf(redm[row * 8 + 2], redm[row * 8 + 3]));
        float c = fmaxf(fmaxf(redm[row * 8 + 4], redm[row * 8 + 5]), fmaxf(redm[row * 8 + 6], redm[row * 8 + 7]));
        rowmax[r] = fmaxf(a, c);
    }
    float P[2][4], psum[4];
#pragma unroll
    for (int r = 0; r < 4; r++) {
#pragma unroll
        for (int nt = 0; nt < 2; nt++) P[nt][r] = __expf(S[nt][r] - rowmax[r]);
        psum[r] = P[0][r] + P[1][r];
    }
#pragma unroll
    for (int mk = 1; mk < 16; mk <<= 1)
#pragma unroll
        for (int r = 0; r < 4; r++) psum[r] += __shfl_xor(psum[r], mk);
    if (lm == 0) {
#pragma unroll
        for (int r = 0; r < 4; r++) reds[(lq * 4 + r) * 8 + w] = psum[r];
    }
    __syncthreads();
    float inv[4];
#pragma unroll
    for (int r = 0; r < 4; r++) {
        int row = lq * 4 + r;
        float a = (reds[row * 8 + 0] + reds[row * 8 + 1]) + (reds[row * 8 + 2] + reds[row * 8 + 3]);
        float c = (reds[row * 8 + 4] + reds[row * 8 + 5]) + (reds[row * 8 + 6] + reds[row * 8 + 7]);
        inv[r] = 1.f / (a + c);
    }
    // probs: bf16 into A2 (MFMA2 A-operand, swizzled) and into wgbf for K5
#pragma unroll
    for (int nt = 0; nt < 2; nt++)
#pragma unroll
        for (int r = 0; r < 4; r++) {
            int row = lq * 4 + r;
            int col = w * 32 + nt * 16 + lm;
            float pv = P[nt][r] * inv[r];
            unsigned short pb = f2bf(pv);
            A2[row * 256 + swz(row, col)] = pb;
            if (row < 12) wgbf[wbase + (size_t)row * (Nn * Nn) + col] = pb;
        }
    __syncthreads();   // A2 + SVTh(half1) ready

    // ---- MFMA2a (waves 0..1): d-tiles 0,1 from SVTh half 1 ----
    if (w < 2) {
        f32x4 acc2 = (f32x4){0.f, 0.f, 0.f, 0.f};
#pragma unroll
        for (int ks = 0; ks < 8; ks++) {
            bhalf8 af = *(const bhalf8*)(A2 + lm * 256 + swz(lm, ks * 32 + lq * 8));
            int vrow = w * 16 + lm;      // 0..31
            bhalf8 bf = *(const bhalf8*)(SVTh + vrow * 256 + swz(vrow, ks * 32 + lq * 8));
            acc2 = __builtin_amdgcn_mfma_f32_16x16x32_bf16(af, bf, acc2, 0, 0, 0);
        }
#pragma unroll
        for (int r = 0; r < 4; r++) {
            int row = lq * 4 + r;
            if (row < 12) attn[(size_t)bq * Hh + row * 64 + w * 16 + lm] = acc2[r];
        }
    }
    __syncthreads();   // half1 consumed

    // SVT half 2: d in [32,64)  (accSV nt 2..3), stored at SVTh rows d-32
#pragma unroll
    for (int mi = 0; mi < 2; mi++)
#pragma unroll
        for (int nt = 2; nt < 4; nt++) {
            int d = nt * 16 + lm;
            int dr = d - 32;
            float bb = bskv2[64 + d];
#pragma unroll
            for (int rr = 0; rr < 4; rr++) {
                int R2 = w * 32 + mi * 16 + lq * 4 + rr;
                SVTh[dr * 256 + swz(dr, R2)] = f2bf(accSV[mi][nt][rr] + bb);
            }
        }
    __syncthreads();   // half2 ready (A2 untouched)

    // ---- MFMA2b (waves 2..3): d-tiles 2,3 from SVTh half 2 ----
    if (w >= 2 && w < 4) {
        f32x4 acc2 = (f32x4){0.f, 0.f, 0.f, 0.f};
#pragma unroll
        for (int ks = 0; ks < 8; ks++) {
            bhalf8 af = *(const bhalf8*)(A2 + lm * 256 + swz(lm, ks * 32 + lq * 8));
            int vrow = (w - 2) * 16 + lm;   // 0..31 within half2
            bhalf8 bf = *(const bhalf8*)(SVTh + vrow * 256 + swz(vrow, ks * 32 + lq * 8));
            acc2 = __builtin_amdgcn_mfma_f32_16x16x32_bf16(af, bf, acc2, 0, 0, 0);
        }
#pragma unroll
        for (int r = 0; r < 4; r++) {
            int row = lq * 4 + r;
            if (row < 12) attn[(size_t)bq * Hh + row * 64 + w * 16 + lm] = acc2[r];
        }
    }
}

// ---------------- K5: content out = P(bf16) @ V(bf16), MFMA, accumulate into attn ----------------
__global__ __launch_bounds__(256) void k_ctxout(const unsigned short* __restrict__ wgbf, // [b,h,q,k] bf16
                                                const unsigned short* __restrict__ vt,   // [b,h,d,k] bf16
                                                float* __restrict__ attn) {
    __shared__ __align__(16) unsigned short Alds[64 * 72];
    __shared__ __align__(16) unsigned short Blds[64 * 72];
    int tid = threadIdx.x;
    int bh = blockIdx.y;
    int m0 = blockIdx.x * 64;
    int b = bh / 12, h = bh % 12;
    int w = tid >> 6, lane = tid & 63, lm = lane & 15, lq = lane >> 4;
    f32x4 acc[4];
#pragma unroll
    for (int i = 0; i < 4; i++) acc[i] = (f32x4){0.f, 0.f, 0.f, 0.f};
    const unsigned short* Abase = wgbf + ((size_t)bh * Nn + m0) * Nn;
    const unsigned short* Bbase = vt + (size_t)bh * Dd * Nn;
    for (int kt = 0; kt < 256; kt += 64) {
#pragma unroll
        for (int t = 0; t < 2; t++) {
            int c = t * 256 + tid;
            int row = c >> 3, kc = c & 7;
            *(uint4*)(Alds + row * 72 + kc * 8) = *(const uint4*)(Abase + (size_t)row * Nn + kt + kc * 8);
            *(uint4*)(Blds + row * 72 + kc * 8) = *(const uint4*)(Bbase + (size_t)row * Nn + kt + kc * 8);
        }
        __syncthreads();
#pragma unroll
        for (int ks = 0; ks < 2; ks++) {
            bhalf8 af = *(const bhalf8*)(Alds + (w * 16 + lm) * 72 + ks * 32 + lq * 8);
#pragma unroll
            for (int nt = 0; nt < 4; nt++) {
                bhalf8 bf = *(const bhalf8*)(Blds + (nt * 16 + lm) * 72 + ks * 32 + lq * 8);
                acc[nt] = __builtin_amdgcn_mfma_f32_16x16x32_bf16(af, bf, acc[nt], 0, 0, 0);
            }
        }
        __syncthreads();
    }
#pragma unroll
    for (int nt = 0; nt < 4; nt++)
#pragma unroll
        for (int r = 0; r < 4; r++) {
            int row = m0 + w * 16 + lq * 4 + r;
            int col = nt * 16 + lm;
            size_t o = ((size_t)b * Nn + row) * Hh + h * 64 + col;
            attn[o] += acc[nt][r];
        }
}

// ---------------- K6: out projection + bias + relu + residual, MFMA (32x64 tiles, 768 blocks) ----------------
__global__ __launch_bounds__(256) void k_outproj(const float* __restrict__ attn,
                                                 const unsigned short* __restrict__ Wot, // [768][768] n-major
                                                 const float* __restrict__ bo,
                                                 const float* __restrict__ nodes,
                                                 float* __restrict__ tmp) {
    __shared__ __align__(16) unsigned short Alds[32 * 72];
    __shared__ __align__(16) unsigned short Blds[64 * 72];
    int tid = threadIdx.x;
    int m0 = blockIdx.y * 32;
    int n0 = blockIdx.x * 64;
    int w = tid >> 6, lane = tid & 63;
    int wm = w >> 1, wn = w & 1;
    int lm = lane & 15, lq = lane >> 4;
    f32x4 acc[2];
#pragma unroll
    for (int j = 0; j < 2; j++) acc[j] = (f32x4){0.f, 0.f, 0.f, 0.f};
    for (int kt = 0; kt < 768; kt += 64) {
#pragma unroll
        for (int t = 0; t < 2; t++) {  // A: 32x64 fp32 -> bf16
            int c = t * 256 + tid;
            int row = c >> 4, cc = c & 15;
            float4 v = *(const float4*)(attn + (size_t)(m0 + row) * 768 + kt + cc * 4);
            uint2 uu;
            uu.x = (unsigned)f2bf(v.x) | ((unsigned)f2bf(v.y) << 16);
            uu.y = (unsigned)f2bf(v.z) | ((unsigned)f2bf(v.w) << 16);
            *(uint2*)(Alds + row * 72 + cc * 4) = uu;
        }
#pragma unroll
        for (int t = 0; t < 2; t++) {  // B: 64x64 bf16
            int c = t * 256 + tid;
            int n = c >> 3, kc = c & 7;
            uint4 v = *(const uint4*)(Wot + (size_t)(n0 + n) * 768 + kt + kc * 8);
            *(uint4*)(Blds + n * 72 + kc * 8) = v;
        }
        __syncthreads();
#pragma unroll
        for (int ks = 0; ks < 2; ks++) {
            bhalf8 af = *(const bhalf8*)(Alds + (wm * 16 + lm) * 72 + ks * 32 + lq * 8);
#pragma unroll
            for (int nt = 0; nt < 2; nt++) {
                bhalf8 bf = *(const bhalf8*)(Blds + (wn * 32 + nt * 16 + lm) * 72 + ks * 32 + lq * 8);
                acc[nt] = __builtin_amdgcn_mfma_f32_16x16x32_bf16(af, bf, acc[nt], 0, 0, 0);
            }
        }
        __syncthreads();
    }
#pragma unroll
    for (int nt = 0; nt < 2; nt++)
#pragma unroll
        for (int r = 0; r < 4; r++) {
            int row = m0 + wm * 16 + lq * 4 + r;
            int col = n0 + wn * 32 + nt * 16 + lm;
            float val = acc[nt][r] + bo[col];
            val = fmaxf(val, 0.f) + nodes[(size_t)row * 768 + col];
            tmp[(size_t)row * 768 + col] = val;
        }
}

// ---------------- K7: final row LayerNorm ----------------
__global__ __launch_bounds__(256) void k_finalln(const float* __restrict__ tmp,
                                                 const float* __restrict__ go,
                                                 const float* __restrict__ bout,
                                                 float* __restrict__ out) {
    __shared__ float rs1[4], rs2[4];
    int m = blockIdx.x, tid = threadIdx.x;
    int lane = tid & 63, wid = tid >> 6;
    const float* row = tmp + (size_t)m * 768;
    float x0 = row[tid], x1 = row[tid + 256], x2 = row[tid + 512];
    float s = x0 + x1 + x2;
    float s2 = x0 * x0 + x1 * x1 + x2 * x2;
#pragma unroll
    for (int mk = 32; mk; mk >>= 1) {
        s += __shfl_xor(s, mk);
        s2 += __shfl_xor(s2, mk);
    }
    if (lane == 0) { rs1[wid] = s; rs2[wid] = s2; }
    __syncthreads();
    s = rs1[0] + rs1[1] + rs1[2] + rs1[3];
    s2 = rs2[0] + rs2[1] + rs2[2] + rs2[3];
    float mu = s * (1.f / 768.f);
    float var = s2 * (1.f / 768.f) - mu * mu;
    float rstd = rsqrtf(var + EPSf);
    float* orow = out + (size_t)m * 768;
    orow[tid] = (x0 - mu) * rstd * go[tid] + bout[tid];
    orow[tid + 256] = (x1 - mu) * rstd * go[tid + 256] + bout[tid + 256];
    orow[tid + 512] = (x2 - mu) * rstd * go[tid + 512] + bout[tid + 512];
}

extern "C" void kernel_launch(void* const* d_in, const int* in_sizes, int n_in,
                              void* d_out, int out_size, void* d_ws, size_t ws_size,
                              hipStream_t stream) {
    const float* nodes = (const float*)d_in[0];
    const float* bias  = (const float*)d_in[1];
    const float* paths = (const float*)d_in[2];
    const float* Wq = (const float*)d_in[3];  const float* bq  = (const float*)d_in[4];
    const float* Wk = (const float*)d_in[5];  const float* bk  = (const float*)d_in[6];
    const float* Wv = (const float*)d_in[7];  const float* bv  = (const float*)d_in[8];
    const float* Wsk = (const float*)d_in[9]; const float* bsk = (const float*)d_in[10];
    const float* Wsv = (const float*)d_in[11];const float* bsv = (const float*)d_in[12];
    const float* Wo = (const float*)d_in[13]; const float* bo  = (const float*)d_in[14];
    const float* gp = (const float*)d_in[15]; const float* bp  = (const float*)d_in[16];
    const float* go = (const float*)d_in[17]; const float* bout= (const float*)d_in[18];
    float* out = (float*)d_out;

    char* ws = (char*)d_ws;
    size_t off = 0;
    auto carve = [&](size_t bytes) -> char* {
        char* p = ws + off;
        off += (bytes + 255) & ~(size_t)255;
        return p;
    };
    float* qs   = (float*)carve((size_t)Bb * HEADS * Nn * Dd * 4);
    float* kk   = (float*)carve((size_t)Bb * HEADS * Nn * Dd * 4);
    unsigned short* vt = (unsigned short*)carve((size_t)Bb * HEADS * Dd * Nn * 2);
    float* wg   = (float*)carve((size_t)Bb * HEADS * Nn * Nn * 4);
    unsigned short* wgbf = (unsigned short*)carve((size_t)Bb * HEADS * Nn * Nn * 2);
    float* attn = (float*)carve((size_t)Bb * Nn * Hh * 4);
    float* tmp  = (float*)carve((size_t)Bb * Nn * Hh * 4);
    unsigned short* Wqkvt = (unsigned short*)carve((size_t)3 * 768 * 768 * 2);
    unsigned short* Wot   = (unsigned short*)carve((size_t)768 * 768 * 2);
    unsigned short* Wskvt = (unsigned short*)carve((size_t)128 * 128 * 2);
    float* bskv2 = (float*)carve(128 * 4);
    (void)ws_size; (void)in_sizes; (void)n_in; (void)out_size;

    // K0: weight transposes (fp32 -> bf16, n-major); g_path folded into Wskvt; bias' = bp@W + bskv
    hipLaunchKernelGGL(k_transpose4, dim3(24, 24, 4), dim3(256), 0, stream,
                       Wq, Wk, Wv, Wo,
                       Wqkvt, Wqkvt + (size_t)768 * 768, Wqkvt + (size_t)2 * 768 * 768, Wot);
    hipLaunchKernelGGL(k_transpose_small, dim3(2, 4, 2), dim3(256), 0, stream,
                       Wsk, Wsv, gp, Wskvt, Wskvt + (size_t)64 * 128);
    hipLaunchKernelGGL(k_prep_bias, dim3(1), dim3(128), 0, stream,
                       Wsk, Wsv, bp, bsk, bsv, bskv2);

    // K1: QKV (V -> bf16 transposed vt)
    hipLaunchKernelGGL(k_qkv, dim3(18, 32), dim3(256), 0, stream, nodes, Wqkvt, bq, bk, bv, qs, kk, vt);
    // K2: content scores + bias (fp32)
    hipLaunchKernelGGL(k_scores, dim3(4, 4, 96), dim3(256), 0, stream, qs, kk, bias, wg);
    // K4 (fused, 512 thr): path LN + struct proj + struct scores + softmax + struct out
    hipLaunchKernelGGL(k_attn, dim3(2048), dim3(512), 0, stream, qs, paths, Wskvt, bskv2, wg, wgbf, attn);
    // K5: content out accumulate (MFMA bf16)
    hipLaunchKernelGGL(k_ctxout, dim3(4, 96), dim3(256), 0, stream, wgbf, vt, attn);
    // K6: output projection + relu + residual (32x64 tiles, 768 blocks = 3/CU)
    hipLaunchKernelGGL(k_outproj, dim3(12, 64), dim3(256), 0, stream, attn, Wot, bo, nodes, tmp);
    // K7: final layernorm
    hipLaunchKernelGGL(k_finalln, dim3(2048), dim3(256), 0, stream, tmp, go, bout, out);
}